// Round 8
// baseline (1568.616 us; speedup 1.0000x reference)
//
#include <hip/hip_runtime.h>

typedef unsigned short u16;
typedef unsigned int u32;
typedef __attribute__((ext_vector_type(8))) short shortx8;
typedef __attribute__((ext_vector_type(4))) float floatx4;
typedef __attribute__((ext_vector_type(4))) u32 uintx4;
typedef __attribute__((ext_vector_type(2))) u32 uintx2;

#define AS1 __attribute__((address_space(1)))
#define AS3 __attribute__((address_space(3)))

__device__ __forceinline__ float bf2f(u16 u) {
  return __builtin_bit_cast(float, ((u32)u) << 16);
}
__device__ __forceinline__ u16 f2bf(float f) {
  u32 i = __builtin_bit_cast(u32, f);
  u32 r = (i + 0x7fffu + ((i >> 16) & 1u)) >> 16;  // RNE
  return (u16)r;
}

// ---------------------------------------------------------------------------
// Coalesced packing: 64x64 LDS-tile transpose, fp32 -> bf16. (r7, measured-good)
// ---------------------------------------------------------------------------
__launch_bounds__(256)
__global__ void pack_qkv_t(const float* __restrict__ W, u16* __restrict__ dst) {
  __shared__ u16 T[64][72];
  const int kt = blockIdx.x, y = blockIdx.y;
  const int l = y >> 4, h = y & 15;
  const int t = threadIdx.x;
  const int rr = t >> 2, cq = (t & 3) * 16;
  const float* src = W + ((size_t)y * 1024 + kt * 64 + rr) * 64 + cq;
#pragma unroll
  for (int e4 = 0; e4 < 4; ++e4) {
    float4 f = *(const float4*)(src + e4 * 4);
    T[cq + e4 * 4 + 0][rr] = f2bf(f.x);
    T[cq + e4 * 4 + 1][rr] = f2bf(f.y);
    T[cq + e4 * 4 + 2][rr] = f2bf(f.z);
    T[cq + e4 * 4 + 3][rr] = f2bf(f.w);
  }
  __syncthreads();
  const int dd = t >> 2, kq = (t & 3) * 16;
  u16* drow = dst + (size_t)l * 3145728 + ((size_t)h * 64 + dd) * 1024 + kt * 64 + kq;
  *(uintx4*)(drow) = *(const uintx4*)&T[dd][kq];
  *(uintx4*)(drow + 8) = *(const uintx4*)&T[dd][kq + 8];
}

__launch_bounds__(256)
__global__ void pack_sq_t(const float* __restrict__ W, u16* __restrict__ dst) {
  __shared__ u16 T[64][72];
  const int ct = blockIdx.x & 15, rt = blockIdx.x >> 4, l = blockIdx.y;
  const int t = threadIdx.x;
  const int rr = t >> 2, cq = (t & 3) * 16;
  const float* src = W + (size_t)l * 1048576 + (size_t)(rt * 64 + rr) * 1024 + ct * 64 + cq;
#pragma unroll
  for (int e4 = 0; e4 < 4; ++e4) {
    float4 f = *(const float4*)(src + e4 * 4);
    T[cq + e4 * 4 + 0][rr] = f2bf(f.x);
    T[cq + e4 * 4 + 1][rr] = f2bf(f.y);
    T[cq + e4 * 4 + 2][rr] = f2bf(f.z);
    T[cq + e4 * 4 + 3][rr] = f2bf(f.w);
  }
  __syncthreads();
  const int cc = t >> 2, rq = (t & 3) * 16;
  u16* drow = dst + (size_t)l * 1048576 + (size_t)(ct * 64 + cc) * 1024 + rt * 64 + rq;
  *(uintx4*)(drow) = *(const uintx4*)&T[cc][rq];
  *(uintx4*)(drow + 8) = *(const uintx4*)&T[cc][rq + 8];
}

__launch_bounds__(256)
__global__ void pack_bias(const float* __restrict__ bq, const float* __restrict__ bk,
                          const float* __restrict__ bv, float* __restrict__ bias) {
  const int i = blockIdx.x * 256 + threadIdx.x;  // [0, 6144)
  const int l = i / 3072, n = i % 3072;
  const int which = n >> 10, nn = n & 1023;
  const float* s = (which == 0) ? bq : (which == 1) ? bk : bv;
  bias[i] = s[l * 1024 + nn];
}

// ---------------------------------------------------------------------------
// enc_in: h[m][n] = x[m][:9] @ W[:9][n] + b[n]   (fp32 in, bf16 out)
// ---------------------------------------------------------------------------
__launch_bounds__(256)
__global__ void enc_kernel(const float* __restrict__ x, const float* __restrict__ W,
                           const float* __restrict__ bias, u16* __restrict__ h) {
  const size_t i = (size_t)blockIdx.x * 256 + threadIdx.x;  // 19200*1024
  const int m = (int)(i >> 10), n = (int)(i & 1023);
  const float* xr = x + (size_t)m * 9;
  float acc = bias[n];
#pragma unroll
  for (int f = 0; f < 9; ++f) acc += xr[f] * W[f * 1024 + n];
  h[i] = f2bf(acc);
}

// ---------------------------------------------------------------------------
// GEMM: C[m][n] = A[m][:] . Bt[n][:] (+bias, +residual / +ELU), K=1024 fixed.
// 128x128 tile, BK=64, 4 waves (2x2), mfma_f32_16x16x32_bf16.
// T3-minimum 2-phase pipeline: double-buffered LDS, STAGE(t+1) issued BEFORE
// consuming buf t, ONE barrier per K-step (compiler's vmcnt(0) drain at the
// barrier lands after compute -> DMA latency hidden under MFMA).
// Epilogue: direct store (r6 measured-good; r7 LDS-staged variant regressed).
// EPI: 0 = bias; 1 = bias + residual R; 2 = bias + ELU
// ---------------------------------------------------------------------------
template <int EPI>
__launch_bounds__(256)
__global__ void gemm_bt(const u16* __restrict__ A, int lda,
                        const u16* __restrict__ Bt,
                        const float* __restrict__ bias,
                        const u16* __restrict__ R, int ldr,
                        u16* __restrict__ C, int ldc) {
  constexpr int K = 1024;
  constexpr int NT = K / 64;  // 16 K-tiles
  __shared__ u16 As[2][128 * 64];
  __shared__ u16 Bs[2][128 * 64];
  const int tid = threadIdx.x;
  const int lane = tid & 63;
  const int w = tid >> 6;
  const int wr = w >> 1, wc = w & 1;
  const int m0 = blockIdx.y * 128, n0 = blockIdx.x * 128;

  floatx4 acc[4][4];
#pragma unroll
  for (int i = 0; i < 4; ++i)
#pragma unroll
    for (int j = 0; j < 4; ++j) acc[i][j] = (floatx4){0.f, 0.f, 0.f, 0.f};

  const u16* Ab = A + (size_t)m0 * lda;
  const u16* Bb = Bt + (size_t)n0 * K;

  auto STAGE = [&](int buf, int k0) {
#pragma unroll
    for (int p = 0; p < 4; ++p) {
      const int o = p * 4096 + tid * 16;  // byte offset into 16KB half
      const int row = o >> 7;             // 128 B per row
      const int ke = (o & 127) >> 1;      // elem offset in row
      __builtin_amdgcn_global_load_lds((const AS1 void*)(Ab + (size_t)row * lda + (k0 + ke)),
                                       (AS3 void*)((char*)&As[buf][0] + o), 16, 0, 0);
      __builtin_amdgcn_global_load_lds((const AS1 void*)(Bb + (size_t)row * K + (k0 + ke)),
                                       (AS3 void*)((char*)&Bs[buf][0] + o), 16, 0, 0);
    }
  };

  STAGE(0, 0);
  __syncthreads();  // drains vmcnt(0): buf0 ready
  int cur = 0;
  for (int t = 0; t < NT; ++t) {
    if (t + 1 < NT) STAGE(cur ^ 1, (t + 1) * 64);  // overlap DMA with compute
    const u16* Ac = As[cur];
    const u16* Bc = Bs[cur];
#pragma unroll
    for (int ks = 0; ks < 2; ++ks) {
      shortx8 af[4], bfr[4];
#pragma unroll
      for (int i = 0; i < 4; ++i) {
        const int ar = wr * 64 + i * 16 + (lane & 15);
        af[i] = *(const shortx8*)&Ac[ar * 64 + ks * 32 + (lane >> 4) * 8];
        const int br = wc * 64 + i * 16 + (lane & 15);
        bfr[i] = *(const shortx8*)&Bc[br * 64 + ks * 32 + (lane >> 4) * 8];
      }
#pragma unroll
      for (int i = 0; i < 4; ++i)
#pragma unroll
        for (int j = 0; j < 4; ++j)
          acc[i][j] = __builtin_amdgcn_mfma_f32_16x16x32_bf16(af[i], bfr[j], acc[i][j], 0, 0, 0);
    }
    __syncthreads();  // all waves' DMA for buf cur^1 drained; cur free for re-stage
    cur ^= 1;
  }

  // epilogue: C/D layout col=lane&15, row=(lane>>4)*4+r  [validated r1/r2/r3]
  const int lr = (lane >> 4) * 4, lc = lane & 15;
#pragma unroll
  for (int i = 0; i < 4; ++i) {
#pragma unroll
    for (int j = 0; j < 4; ++j) {
      const int col = n0 + wc * 64 + j * 16 + lc;
      const float bv = bias[col];
#pragma unroll
      for (int r = 0; r < 4; ++r) {
        const int row = m0 + wr * 64 + i * 16 + lr + r;
        float v = acc[i][j][r] + bv;
        if (EPI == 1) v += bf2f(R[(size_t)row * ldr + col]);
        if (EPI == 2) v = v > 0.f ? v : expm1f(v);
        C[(size_t)row * ldc + col] = f2bf(v);
      }
    }
  }
}

// ---------------------------------------------------------------------------
// MFMA flash attention (r6 — validated, unchanged).
// ---------------------------------------------------------------------------
__launch_bounds__(256)
__global__ void attn_mfma(const u16* __restrict__ qkv, u16* __restrict__ aout) {
  const int qt = blockIdx.x, bh = blockIdx.y;
  const int b = bh >> 4, h = bh & 15;
  const int tid = threadIdx.x, lane = tid & 63, w = tid >> 6;
  const int g = lane >> 4, lq = lane & 15;

  __shared__ u16 K_ld[128 * 72];
  __shared__ u16 Vt[64 * 136];
  __shared__ u16 P_ld[4][16 * 136];

  const size_t bbase = (size_t)b * 600 * 3072;
  const int q0 = qt * 64 + w * 16;

  shortx8 aq[2];
  {
    const int s = q0 + lq;
    if (s < 600) {
      const u16* qp = qkv + bbase + (size_t)s * 3072 + h * 64 + g * 8;
      aq[0] = *(const shortx8*)qp;
      aq[1] = *(const shortx8*)(qp + 32);
    } else {
      aq[0] = (shortx8){0, 0, 0, 0, 0, 0, 0, 0};
      aq[1] = (shortx8){0, 0, 0, 0, 0, 0, 0, 0};
    }
  }

  floatx4 Oa[4];
#pragma unroll
  for (int db = 0; db < 4; ++db) Oa[db] = (floatx4){0.f, 0.f, 0.f, 0.f};
  float m[4], l[4];
#pragma unroll
  for (int r = 0; r < 4; ++r) { m[r] = -1e30f; l[r] = 0.f; }

  for (int ch = 0; ch < 5; ++ch) {
    const int t0 = ch * 128;
    __syncthreads();
    {
      const int tloc = tid >> 1, dhalf = (tid & 1) * 32;
      const int tg = t0 + tloc;
      if (tg < 600) {
        const u16* kp = qkv + bbase + (size_t)tg * 3072 + 1024 + h * 64 + dhalf;
        const u16* vp = kp + 1024;
#pragma unroll
        for (int c = 0; c < 4; ++c)
          *(uintx4*)&K_ld[tloc * 72 + dhalf + c * 8] = *(const uintx4*)(kp + c * 8);
#pragma unroll
        for (int c = 0; c < 4; ++c) {
          shortx8 vv = *(const shortx8*)(vp + c * 8);
#pragma unroll
          for (int e = 0; e < 8; ++e)
            Vt[(dhalf + c * 8 + e) * 136 + tloc] = (u16)vv[e];
        }
      } else {
        const uintx4 z4 = (uintx4){0, 0, 0, 0};
#pragma unroll
        for (int c = 0; c < 4; ++c)
          *(uintx4*)&K_ld[tloc * 72 + dhalf + c * 8] = z4;
#pragma unroll
        for (int c = 0; c < 4; ++c)
#pragma unroll
          for (int e = 0; e < 8; ++e)
            Vt[(dhalf + c * 8 + e) * 136 + tloc] = 0;
      }
    }
    __syncthreads();

    floatx4 S[8];
#pragma unroll
    for (int jb = 0; jb < 8; ++jb) {
      S[jb] = (floatx4){0.f, 0.f, 0.f, 0.f};
#pragma unroll
      for (int ks = 0; ks < 2; ++ks) {
        shortx8 bk = *(const shortx8*)&K_ld[(jb * 16 + lq) * 72 + ks * 32 + g * 8];
        S[jb] = __builtin_amdgcn_mfma_f32_16x16x32_bf16(aq[ks], bk, S[jb], 0, 0, 0);
      }
    }
#pragma unroll
    for (int jb = 0; jb < 8; ++jb) {
      const int tg = t0 + jb * 16 + lq;
      const bool ok = tg < 600;
#pragma unroll
      for (int r = 0; r < 4; ++r) S[jb][r] = ok ? S[jb][r] * 0.125f : -1e30f;
    }

    float scale[4];
#pragma unroll
    for (int r = 0; r < 4; ++r) {
      float v = S[0][r];
#pragma unroll
      for (int jb = 1; jb < 8; ++jb) v = fmaxf(v, S[jb][r]);
      v = fmaxf(v, __shfl_xor(v, 1));
      v = fmaxf(v, __shfl_xor(v, 2));
      v = fmaxf(v, __shfl_xor(v, 4));
      v = fmaxf(v, __shfl_xor(v, 8));
      const float mn = fmaxf(m[r], v);
      scale[r] = __expf(m[r] - mn);
      m[r] = mn;
      l[r] *= scale[r];
    }
#pragma unroll
    for (int db = 0; db < 4; ++db)
#pragma unroll
      for (int r = 0; r < 4; ++r) Oa[db][r] *= scale[r];

    float sums[4] = {0.f, 0.f, 0.f, 0.f};
#pragma unroll
    for (int jb = 0; jb < 8; ++jb)
#pragma unroll
      for (int r = 0; r < 4; ++r) {
        const float p = __expf(S[jb][r] - m[r]);
        sums[r] += p;
        P_ld[w][(g * 4 + r) * 136 + jb * 16 + lq] = f2bf(p);
      }
#pragma unroll
    for (int r = 0; r < 4; ++r) {
      float v = sums[r];
      v += __shfl_xor(v, 1);
      v += __shfl_xor(v, 2);
      v += __shfl_xor(v, 4);
      v += __shfl_xor(v, 8);
      l[r] += v;
    }

#pragma unroll
    for (int ks = 0; ks < 4; ++ks) {
      shortx8 ap = *(const shortx8*)&P_ld[w][lq * 136 + ks * 32 + g * 8];
#pragma unroll
      for (int db = 0; db < 4; ++db) {
        shortx8 bv = *(const shortx8*)&Vt[(db * 16 + lq) * 136 + ks * 32 + g * 8];
        Oa[db] = __builtin_amdgcn_mfma_f32_16x16x32_bf16(ap, bv, Oa[db], 0, 0, 0);
      }
    }
  }

#pragma unroll
  for (int r = 0; r < 4; ++r) {
    const int sg = q0 + g * 4 + r;
    if (sg < 600) {
      const float inv = 1.f / l[r];
      u16* orow = aout + ((size_t)(b * 600 + sg)) * 1024 + h;
#pragma unroll
      for (int db = 0; db < 4; ++db)
        orow[(size_t)(db * 16 + lq) * 16] = f2bf(Oa[db][r] * inv);
    }
  }
}

// ---------------------------------------------------------------------------
// LayerNorm over 1024 (strided rows): one block per row, biased var, eps 1e-5.
// ---------------------------------------------------------------------------
__launch_bounds__(256)
__global__ void ln_kernel(const u16* __restrict__ y, int ldy,
                          const float* __restrict__ g, const float* __restrict__ be,
                          u16* __restrict__ o, int ldo) {
  const int row = blockIdx.x, tid = threadIdx.x;
  const int lane = tid & 63, wv = tid >> 6;
  const u16* yr = y + (size_t)row * ldy;
  const int c = tid * 4;
  const uintx2 yv = *(const uintx2*)&yr[c];
  float v0 = bf2f((u16)(yv[0] & 0xffffu)), v1 = bf2f((u16)(yv[0] >> 16));
  float v2 = bf2f((u16)(yv[1] & 0xffffu)), v3 = bf2f((u16)(yv[1] >> 16));
  float s = v0 + v1 + v2 + v3;
  float q = v0 * v0 + v1 * v1 + v2 * v2 + v3 * v3;
#pragma unroll
  for (int m = 32; m; m >>= 1) {
    s += __shfl_xor(s, m);
    q += __shfl_xor(q, m);
  }
  __shared__ float red[2][4];
  if (lane == 0) {
    red[0][wv] = s;
    red[1][wv] = q;
  }
  __syncthreads();
  s = red[0][0] + red[0][1] + red[0][2] + red[0][3];
  q = red[1][0] + red[1][1] + red[1][2] + red[1][3];
  const float mu = s * (1.f / 1024.f);
  const float var = q * (1.f / 1024.f) - mu * mu;
  const float rstd = rsqrtf(var + 1e-5f);
  const float4 gv = *(const float4*)&g[c];
  const float4 bev = *(const float4*)&be[c];
  const float o0 = (v0 - mu) * rstd * gv.x + bev.x;
  const float o1 = (v1 - mu) * rstd * gv.y + bev.y;
  const float o2 = (v2 - mu) * rstd * gv.z + bev.z;
  const float o3 = (v3 - mu) * rstd * gv.w + bev.w;
  uintx2 ov;
  ov[0] = (u32)f2bf(o0) | ((u32)f2bf(o1) << 16);
  ov[1] = (u32)f2bf(o2) | ((u32)f2bf(o3) << 16);
  *(uintx2*)&o[(size_t)row * ldo + c] = ov;
}

// ---------------------------------------------------------------------------
// out: out[m][f] = h[m][:] . outW[:][f] + outb[f], f<9. One wave per row. fp32 out.
// ---------------------------------------------------------------------------
__launch_bounds__(256)
__global__ void out_kernel(const u16* __restrict__ h, const float* __restrict__ W,
                           const float* __restrict__ bias, float* __restrict__ out) {
  const int m = blockIdx.x * 4 + (threadIdx.x >> 6);
  const int lane = threadIdx.x & 63;
  float acc[9];
#pragma unroll
  for (int f = 0; f < 9; ++f) acc[f] = 0.f;
  const u16* hr = h + (size_t)m * 1024;
#pragma unroll 4
  for (int j = 0; j < 16; ++j) {
    const int k = lane + j * 64;
    const float hv = bf2f(hr[k]);
    const float* wr = W + (size_t)k * 9;
#pragma unroll
    for (int f = 0; f < 9; ++f) acc[f] += hv * wr[f];
  }
#pragma unroll
  for (int f = 0; f < 9; ++f)
#pragma unroll
    for (int mm = 32; mm; mm >>= 1) acc[f] += __shfl_xor(acc[f], mm);
  if (lane < 9) out[(size_t)m * 9 + lane] = acc[lane] + bias[lane];
}

// ---------------------------------------------------------------------------
extern "C" void kernel_launch(void* const* d_in, const int* in_sizes, int n_in,
                              void* d_out, int out_size, void* d_ws, size_t ws_size,
                              hipStream_t stream) {
  (void)in_sizes; (void)n_in; (void)out_size; (void)ws_size;
  const float* x     = (const float*)d_in[0];
  const float* encW  = (const float*)d_in[1];
  const float* encB  = (const float*)d_in[2];
  const float* Wq    = (const float*)d_in[3];
  const float* bq    = (const float*)d_in[4];
  const float* Wk    = (const float*)d_in[5];
  const float* bk    = (const float*)d_in[6];
  const float* Wv    = (const float*)d_in[7];
  const float* bv    = (const float*)d_in[8];
  const float* Wo    = (const float*)d_in[9];
  const float* bo    = (const float*)d_in[10];
  const float* W1    = (const float*)d_in[11];
  const float* b1    = (const float*)d_in[12];
  const float* W2    = (const float*)d_in[13];
  const float* b2    = (const float*)d_in[14];
  const float* ln1w  = (const float*)d_in[15];
  const float* ln1b  = (const float*)d_in[16];
  const float* ln2w  = (const float*)d_in[17];
  const float* ln2b  = (const float*)d_in[18];
  const float* outW  = (const float*)d_in[19];
  const float* outB  = (const float*)d_in[20];
  float* out = (float*)d_out;

  char* ws = (char*)d_ws;
  size_t off = 0;
  auto alloc = [&](size_t bytes) -> void* {
    void* p = ws + off;
    off += (bytes + 255) & ~(size_t)255;
    return p;
  };
  u16* h    = (u16*)alloc(19660800ull * 2);   // [19200][1024]
  u16* qkv  = (u16*)alloc(58982400ull * 2);   // [19200][3072]
  u16* abuf = (u16*)alloc(19660800ull * 2);   // ctx flat [19200][1024]
  u16* Bqkv = (u16*)alloc(6291456ull * 2);    // [2][3072][1024]
  u16* Bwo  = (u16*)alloc(2097152ull * 2);    // [2][1024][1024] transposed
  u16* Bw1  = (u16*)alloc(2097152ull * 2);
  u16* Bw2  = (u16*)alloc(2097152ull * 2);
  float* bqkv = (float*)alloc(6144ull * 4);   // [2][3072] fp32
  // column-slot aliases inside qkv (stride 3072), reusing dead q/k/v slots:
  u16* ybuf = qkv;          // q-slot: Wo-gemm output (q dead after attention)
  u16* x1   = qkv + 1024;   // k-slot: ln1 output
  u16* mid  = qkv + 2048;   // v-slot: fc2/ELU output
  u16* y2   = abuf;         // dense: fc1 output (+x1 residual); abuf dead by then

  pack_qkv_t<<<dim3(16, 32), 256, 0, stream>>>(Wq, Bqkv);
  pack_qkv_t<<<dim3(16, 32), 256, 0, stream>>>(Wk, Bqkv + 1048576);
  pack_qkv_t<<<dim3(16, 32), 256, 0, stream>>>(Wv, Bqkv + 2097152);
  pack_sq_t<<<dim3(256, 2), 256, 0, stream>>>(Wo, Bwo);
  pack_sq_t<<<dim3(256, 2), 256, 0, stream>>>(W1, Bw1);
  pack_sq_t<<<dim3(256, 2), 256, 0, stream>>>(W2, Bw2);
  pack_bias<<<24, 256, 0, stream>>>(bq, bk, bv, bqkv);
  enc_kernel<<<76800, 256, 0, stream>>>(x, encW, encB, h);

  for (int l = 0; l < 2; ++l) {
    gemm_bt<0><<<dim3(24, 150), 256, 0, stream>>>(
        h, 1024, Bqkv + (size_t)l * 3145728, bqkv + l * 3072, nullptr, 0, qkv, 3072);
    attn_mfma<<<dim3(10, 512), 256, 0, stream>>>(qkv, abuf);
    gemm_bt<1><<<dim3(8, 150), 256, 0, stream>>>(
        abuf, 1024, Bwo + (size_t)l * 1048576, bo + l * 1024, h, 1024, ybuf, 3072);
    ln_kernel<<<19200, 256, 0, stream>>>(ybuf, 3072, ln1w + l * 1024, ln1b + l * 1024, x1, 3072);
    gemm_bt<2><<<dim3(8, 150), 256, 0, stream>>>(
        x1, 3072, Bw2 + (size_t)l * 1048576, b2 + l * 1024, nullptr, 0, mid, 3072);
    gemm_bt<1><<<dim3(8, 150), 256, 0, stream>>>(
        mid, 3072, Bw1 + (size_t)l * 1048576, b1 + l * 1024, x1, 3072, y2, 1024);
    ln_kernel<<<19200, 256, 0, stream>>>(y2, 1024, ln2w + l * 1024, ln2b + l * 1024, h, 1024);
  }
  out_kernel<<<4800, 256, 0, stream>>>(h, outW, outB, out);
}

// Round 9
// 1326.883 us; speedup vs baseline: 1.1822x; 1.1822x over previous
//
#include <hip/hip_runtime.h>

typedef unsigned short u16;
typedef unsigned int u32;
typedef __attribute__((ext_vector_type(8))) short shortx8;
typedef __attribute__((ext_vector_type(4))) float floatx4;
typedef __attribute__((ext_vector_type(4))) u32 uintx4;
typedef __attribute__((ext_vector_type(2))) u32 uintx2;

#define AS1 __attribute__((address_space(1)))
#define AS3 __attribute__((address_space(3)))

__device__ __forceinline__ float bf2f(u16 u) {
  return __builtin_bit_cast(float, ((u32)u) << 16);
}
__device__ __forceinline__ u16 f2bf(float f) {
  u32 i = __builtin_bit_cast(u32, f);
  u32 r = (i + 0x7fffu + ((i >> 16) & 1u)) >> 16;  // RNE
  return (u16)r;
}

// ---------------------------------------------------------------------------
// Coalesced packing: 64x64 LDS-tile transpose, fp32 -> bf16. (r7, measured-good)
// ---------------------------------------------------------------------------
__launch_bounds__(256)
__global__ void pack_qkv_t(const float* __restrict__ W, u16* __restrict__ dst) {
  __shared__ u16 T[64][72];
  const int kt = blockIdx.x, y = blockIdx.y;
  const int l = y >> 4, h = y & 15;
  const int t = threadIdx.x;
  const int rr = t >> 2, cq = (t & 3) * 16;
  const float* src = W + ((size_t)y * 1024 + kt * 64 + rr) * 64 + cq;
#pragma unroll
  for (int e4 = 0; e4 < 4; ++e4) {
    float4 f = *(const float4*)(src + e4 * 4);
    T[cq + e4 * 4 + 0][rr] = f2bf(f.x);
    T[cq + e4 * 4 + 1][rr] = f2bf(f.y);
    T[cq + e4 * 4 + 2][rr] = f2bf(f.z);
    T[cq + e4 * 4 + 3][rr] = f2bf(f.w);
  }
  __syncthreads();
  const int dd = t >> 2, kq = (t & 3) * 16;
  u16* drow = dst + (size_t)l * 3145728 + ((size_t)h * 64 + dd) * 1024 + kt * 64 + kq;
  *(uintx4*)(drow) = *(const uintx4*)&T[dd][kq];
  *(uintx4*)(drow + 8) = *(const uintx4*)&T[dd][kq + 8];
}

__launch_bounds__(256)
__global__ void pack_sq_t(const float* __restrict__ W, u16* __restrict__ dst) {
  __shared__ u16 T[64][72];
  const int ct = blockIdx.x & 15, rt = blockIdx.x >> 4, l = blockIdx.y;
  const int t = threadIdx.x;
  const int rr = t >> 2, cq = (t & 3) * 16;
  const float* src = W + (size_t)l * 1048576 + (size_t)(rt * 64 + rr) * 1024 + ct * 64 + cq;
#pragma unroll
  for (int e4 = 0; e4 < 4; ++e4) {
    float4 f = *(const float4*)(src + e4 * 4);
    T[cq + e4 * 4 + 0][rr] = f2bf(f.x);
    T[cq + e4 * 4 + 1][rr] = f2bf(f.y);
    T[cq + e4 * 4 + 2][rr] = f2bf(f.z);
    T[cq + e4 * 4 + 3][rr] = f2bf(f.w);
  }
  __syncthreads();
  const int cc = t >> 2, rq = (t & 3) * 16;
  u16* drow = dst + (size_t)l * 1048576 + (size_t)(ct * 64 + cc) * 1024 + rt * 64 + rq;
  *(uintx4*)(drow) = *(const uintx4*)&T[cc][rq];
  *(uintx4*)(drow + 8) = *(const uintx4*)&T[cc][rq + 8];
}

__launch_bounds__(256)
__global__ void pack_bias(const float* __restrict__ bq, const float* __restrict__ bk,
                          const float* __restrict__ bv, float* __restrict__ bias) {
  const int i = blockIdx.x * 256 + threadIdx.x;  // [0, 6144)
  const int l = i / 3072, n = i % 3072;
  const int which = n >> 10, nn = n & 1023;
  const float* s = (which == 0) ? bq : (which == 1) ? bk : bv;
  bias[i] = s[l * 1024 + nn];
}

// ---------------------------------------------------------------------------
// enc_in: h[m][n] = x[m][:9] @ W[:9][n] + b[n]   (fp32 in, bf16 out)
// ---------------------------------------------------------------------------
__launch_bounds__(256)
__global__ void enc_kernel(const float* __restrict__ x, const float* __restrict__ W,
                           const float* __restrict__ bias, u16* __restrict__ h) {
  const size_t i = (size_t)blockIdx.x * 256 + threadIdx.x;  // 19200*1024
  const int m = (int)(i >> 10), n = (int)(i & 1023);
  const float* xr = x + (size_t)m * 9;
  float acc = bias[n];
#pragma unroll
  for (int f = 0; f < 9; ++f) acc += xr[f] * W[f * 1024 + n];
  h[i] = f2bf(acc);
}

// ---------------------------------------------------------------------------
// GEMM (r6-exact): 128x128 tile, BK=64, 4 waves (2x2), single-buffer,
// global_load_lds, direct epilogue. Proven 203 us (r6); r7/r8 variants slower.
// EPI: 0 = bias; 1 = bias + residual R; 2 = bias + ELU
// ---------------------------------------------------------------------------
template <int EPI>
__launch_bounds__(256)
__global__ void gemm_bt(const u16* __restrict__ A, int lda,
                        const u16* __restrict__ Bt,
                        const float* __restrict__ bias,
                        const u16* __restrict__ R, int ldr,
                        u16* __restrict__ C, int ldc) {
  constexpr int K = 1024;
  __shared__ u16 As[128 * 64];
  __shared__ u16 Bs[128 * 64];
  const int tid = threadIdx.x;
  const int lane = tid & 63;
  const int w = tid >> 6;
  const int wr = w >> 1, wc = w & 1;
  const int m0 = blockIdx.y * 128, n0 = blockIdx.x * 128;

  floatx4 acc[4][4];
#pragma unroll
  for (int i = 0; i < 4; ++i)
#pragma unroll
    for (int j = 0; j < 4; ++j) acc[i][j] = (floatx4){0.f, 0.f, 0.f, 0.f};

  const u16* Ab = A + (size_t)m0 * lda;
  const u16* Bb = Bt + (size_t)n0 * K;

  for (int k0 = 0; k0 < K; k0 += 64) {
#pragma unroll
    for (int p = 0; p < 4; ++p) {
      const int o = p * 4096 + tid * 16;  // byte offset into 16KB tile
      const int row = o >> 7;             // 128 B per row
      const int ke = (o & 127) >> 1;      // elem offset in row
      __builtin_amdgcn_global_load_lds((const AS1 void*)(Ab + (size_t)row * lda + (k0 + ke)),
                                       (AS3 void*)((char*)As + o), 16, 0, 0);
      __builtin_amdgcn_global_load_lds((const AS1 void*)(Bb + (size_t)row * K + (k0 + ke)),
                                       (AS3 void*)((char*)Bs + o), 16, 0, 0);
    }
    __syncthreads();
#pragma unroll
    for (int ks = 0; ks < 2; ++ks) {
      shortx8 af[4], bfr[4];
#pragma unroll
      for (int i = 0; i < 4; ++i) {
        const int ar = wr * 64 + i * 16 + (lane & 15);
        af[i] = *(const shortx8*)&As[ar * 64 + ks * 32 + (lane >> 4) * 8];
        const int br = wc * 64 + i * 16 + (lane & 15);
        bfr[i] = *(const shortx8*)&Bs[br * 64 + ks * 32 + (lane >> 4) * 8];
      }
#pragma unroll
      for (int i = 0; i < 4; ++i)
#pragma unroll
        for (int j = 0; j < 4; ++j)
          acc[i][j] = __builtin_amdgcn_mfma_f32_16x16x32_bf16(af[i], bfr[j], acc[i][j], 0, 0, 0);
    }
    __syncthreads();
  }

  const int lr = (lane >> 4) * 4, lc = lane & 15;
#pragma unroll
  for (int i = 0; i < 4; ++i) {
#pragma unroll
    for (int j = 0; j < 4; ++j) {
      const int col = n0 + wc * 64 + j * 16 + lc;
      const float bv = bias[col];
#pragma unroll
      for (int r = 0; r < 4; ++r) {
        const int row = m0 + wr * 64 + i * 16 + lr + r;
        float v = acc[i][j][r] + bv;
        if (EPI == 1) v += bf2f(R[(size_t)row * ldr + col]);
        if (EPI == 2) v = v > 0.f ? v : expm1f(v);
        C[(size_t)row * ldc + col] = f2bf(v);
      }
    }
  }
}

// ---------------------------------------------------------------------------
// WIDE GEMM for QKV: 128x256 tile, BK=64, 8 waves (2Mx4N), 512 threads,
// single-buffer (r6-proven sync), 48KB LDS. 2x FLOP/byte vs 128^2 — targets
// the staging-bandwidth bound (9 TB/s aggregate observed at 128^2).
// ---------------------------------------------------------------------------
__launch_bounds__(512)
__global__ void gemm_bt_wide(const u16* __restrict__ A, int lda,
                             const u16* __restrict__ Bt,
                             const float* __restrict__ bias,
                             u16* __restrict__ C, int ldc) {
  constexpr int K = 1024;
  __shared__ u16 As[128 * 64];  // 16 KB
  __shared__ u16 Bs[256 * 64];  // 32 KB
  const int tid = threadIdx.x;
  const int lane = tid & 63;
  const int w = tid >> 6;          // 0..7
  const int wr = w >> 2, wc = w & 3;
  const int m0 = blockIdx.y * 128, n0 = blockIdx.x * 256;

  floatx4 acc[4][4];
#pragma unroll
  for (int i = 0; i < 4; ++i)
#pragma unroll
    for (int j = 0; j < 4; ++j) acc[i][j] = (floatx4){0.f, 0.f, 0.f, 0.f};

  const u16* Ab = A + (size_t)m0 * lda;
  const u16* Bb = Bt + (size_t)n0 * K;

  for (int k0 = 0; k0 < K; k0 += 64) {
#pragma unroll
    for (int p = 0; p < 2; ++p) {  // A: 16KB = 512 thr * 16B * 2
      const int o = p * 8192 + tid * 16;
      const int row = o >> 7;
      const int ke = (o & 127) >> 1;
      __builtin_amdgcn_global_load_lds((const AS1 void*)(Ab + (size_t)row * lda + (k0 + ke)),
                                       (AS3 void*)((char*)As + o), 16, 0, 0);
    }
#pragma unroll
    for (int p = 0; p < 4; ++p) {  // B: 32KB = 512 thr * 16B * 4
      const int o = p * 8192 + tid * 16;
      const int row = o >> 7;
      const int ke = (o & 127) >> 1;
      __builtin_amdgcn_global_load_lds((const AS1 void*)(Bb + (size_t)row * K + (k0 + ke)),
                                       (AS3 void*)((char*)Bs + o), 16, 0, 0);
    }
    __syncthreads();
#pragma unroll
    for (int ks = 0; ks < 2; ++ks) {
      shortx8 af[4], bfr[4];
#pragma unroll
      for (int i = 0; i < 4; ++i) {
        const int ar = wr * 64 + i * 16 + (lane & 15);
        af[i] = *(const shortx8*)&As[ar * 64 + ks * 32 + (lane >> 4) * 8];
        const int br = wc * 64 + i * 16 + (lane & 15);
        bfr[i] = *(const shortx8*)&Bs[br * 64 + ks * 32 + (lane >> 4) * 8];
      }
#pragma unroll
      for (int i = 0; i < 4; ++i)
#pragma unroll
        for (int j = 0; j < 4; ++j)
          acc[i][j] = __builtin_amdgcn_mfma_f32_16x16x32_bf16(af[i], bfr[j], acc[i][j], 0, 0, 0);
    }
    __syncthreads();
  }

  const int lr = (lane >> 4) * 4, lc = lane & 15;
#pragma unroll
  for (int i = 0; i < 4; ++i) {
#pragma unroll
    for (int j = 0; j < 4; ++j) {
      const int col = n0 + wc * 64 + j * 16 + lc;
      const float bv = bias[col];
#pragma unroll
      for (int r = 0; r < 4; ++r) {
        const int row = m0 + wr * 64 + i * 16 + lr + r;
        C[(size_t)row * ldc + col] = f2bf(acc[i][j][r] + bv);
      }
    }
  }
}

// ---------------------------------------------------------------------------
// MFMA flash attention (r6 — validated, unchanged).
// ---------------------------------------------------------------------------
__launch_bounds__(256)
__global__ void attn_mfma(const u16* __restrict__ qkv, u16* __restrict__ aout) {
  const int qt = blockIdx.x, bh = blockIdx.y;
  const int b = bh >> 4, h = bh & 15;
  const int tid = threadIdx.x, lane = tid & 63, w = tid >> 6;
  const int g = lane >> 4, lq = lane & 15;

  __shared__ u16 K_ld[128 * 72];
  __shared__ u16 Vt[64 * 136];
  __shared__ u16 P_ld[4][16 * 136];

  const size_t bbase = (size_t)b * 600 * 3072;
  const int q0 = qt * 64 + w * 16;

  shortx8 aq[2];
  {
    const int s = q0 + lq;
    if (s < 600) {
      const u16* qp = qkv + bbase + (size_t)s * 3072 + h * 64 + g * 8;
      aq[0] = *(const shortx8*)qp;
      aq[1] = *(const shortx8*)(qp + 32);
    } else {
      aq[0] = (shortx8){0, 0, 0, 0, 0, 0, 0, 0};
      aq[1] = (shortx8){0, 0, 0, 0, 0, 0, 0, 0};
    }
  }

  floatx4 Oa[4];
#pragma unroll
  for (int db = 0; db < 4; ++db) Oa[db] = (floatx4){0.f, 0.f, 0.f, 0.f};
  float m[4], l[4];
#pragma unroll
  for (int r = 0; r < 4; ++r) { m[r] = -1e30f; l[r] = 0.f; }

  for (int ch = 0; ch < 5; ++ch) {
    const int t0 = ch * 128;
    __syncthreads();
    {
      const int tloc = tid >> 1, dhalf = (tid & 1) * 32;
      const int tg = t0 + tloc;
      if (tg < 600) {
        const u16* kp = qkv + bbase + (size_t)tg * 3072 + 1024 + h * 64 + dhalf;
        const u16* vp = kp + 1024;
#pragma unroll
        for (int c = 0; c < 4; ++c)
          *(uintx4*)&K_ld[tloc * 72 + dhalf + c * 8] = *(const uintx4*)(kp + c * 8);
#pragma unroll
        for (int c = 0; c < 4; ++c) {
          shortx8 vv = *(const shortx8*)(vp + c * 8);
#pragma unroll
          for (int e = 0; e < 8; ++e)
            Vt[(dhalf + c * 8 + e) * 136 + tloc] = (u16)vv[e];
        }
      } else {
        const uintx4 z4 = (uintx4){0, 0, 0, 0};
#pragma unroll
        for (int c = 0; c < 4; ++c)
          *(uintx4*)&K_ld[tloc * 72 + dhalf + c * 8] = z4;
#pragma unroll
        for (int c = 0; c < 4; ++c)
#pragma unroll
          for (int e = 0; e < 8; ++e)
            Vt[(dhalf + c * 8 + e) * 136 + tloc] = 0;
      }
    }
    __syncthreads();

    floatx4 S[8];
#pragma unroll
    for (int jb = 0; jb < 8; ++jb) {
      S[jb] = (floatx4){0.f, 0.f, 0.f, 0.f};
#pragma unroll
      for (int ks = 0; ks < 2; ++ks) {
        shortx8 bk = *(const shortx8*)&K_ld[(jb * 16 + lq) * 72 + ks * 32 + g * 8];
        S[jb] = __builtin_amdgcn_mfma_f32_16x16x32_bf16(aq[ks], bk, S[jb], 0, 0, 0);
      }
    }
#pragma unroll
    for (int jb = 0; jb < 8; ++jb) {
      const int tg = t0 + jb * 16 + lq;
      const bool ok = tg < 600;
#pragma unroll
      for (int r = 0; r < 4; ++r) S[jb][r] = ok ? S[jb][r] * 0.125f : -1e30f;
    }

    float scale[4];
#pragma unroll
    for (int r = 0; r < 4; ++r) {
      float v = S[0][r];
#pragma unroll
      for (int jb = 1; jb < 8; ++jb) v = fmaxf(v, S[jb][r]);
      v = fmaxf(v, __shfl_xor(v, 1));
      v = fmaxf(v, __shfl_xor(v, 2));
      v = fmaxf(v, __shfl_xor(v, 4));
      v = fmaxf(v, __shfl_xor(v, 8));
      const float mn = fmaxf(m[r], v);
      scale[r] = __expf(m[r] - mn);
      m[r] = mn;
      l[r] *= scale[r];
    }
#pragma unroll
    for (int db = 0; db < 4; ++db)
#pragma unroll
      for (int r = 0; r < 4; ++r) Oa[db][r] *= scale[r];

    float sums[4] = {0.f, 0.f, 0.f, 0.f};
#pragma unroll
    for (int jb = 0; jb < 8; ++jb)
#pragma unroll
      for (int r = 0; r < 4; ++r) {
        const float p = __expf(S[jb][r] - m[r]);
        sums[r] += p;
        P_ld[w][(g * 4 + r) * 136 + jb * 16 + lq] = f2bf(p);
      }
#pragma unroll
    for (int r = 0; r < 4; ++r) {
      float v = sums[r];
      v += __shfl_xor(v, 1);
      v += __shfl_xor(v, 2);
      v += __shfl_xor(v, 4);
      v += __shfl_xor(v, 8);
      l[r] += v;
    }

#pragma unroll
    for (int ks = 0; ks < 4; ++ks) {
      shortx8 ap = *(const shortx8*)&P_ld[w][lq * 136 + ks * 32 + g * 8];
#pragma unroll
      for (int db = 0; db < 4; ++db) {
        shortx8 bv = *(const shortx8*)&Vt[(db * 16 + lq) * 136 + ks * 32 + g * 8];
        Oa[db] = __builtin_amdgcn_mfma_f32_16x16x32_bf16(ap, bv, Oa[db], 0, 0, 0);
      }
    }
  }

#pragma unroll
  for (int r = 0; r < 4; ++r) {
    const int sg = q0 + g * 4 + r;
    if (sg < 600) {
      const float inv = 1.f / l[r];
      u16* orow = aout + ((size_t)(b * 600 + sg)) * 1024 + h;
#pragma unroll
      for (int db = 0; db < 4; ++db)
        orow[(size_t)(db * 16 + lq) * 16] = f2bf(Oa[db][r] * inv);
    }
  }
}

// ---------------------------------------------------------------------------
// LayerNorm over 1024 (strided rows): one block per row, biased var, eps 1e-5.
// ---------------------------------------------------------------------------
__launch_bounds__(256)
__global__ void ln_kernel(const u16* __restrict__ y, int ldy,
                          const float* __restrict__ g, const float* __restrict__ be,
                          u16* __restrict__ o, int ldo) {
  const int row = blockIdx.x, tid = threadIdx.x;
  const int lane = tid & 63, wv = tid >> 6;
  const u16* yr = y + (size_t)row * ldy;
  const int c = tid * 4;
  const uintx2 yv = *(const uintx2*)&yr[c];
  float v0 = bf2f((u16)(yv[0] & 0xffffu)), v1 = bf2f((u16)(yv[0] >> 16));
  float v2 = bf2f((u16)(yv[1] & 0xffffu)), v3 = bf2f((u16)(yv[1] >> 16));
  float s = v0 + v1 + v2 + v3;
  float q = v0 * v0 + v1 * v1 + v2 * v2 + v3 * v3;
#pragma unroll
  for (int m = 32; m; m >>= 1) {
    s += __shfl_xor(s, m);
    q += __shfl_xor(q, m);
  }
  __shared__ float red[2][4];
  if (lane == 0) {
    red[0][wv] = s;
    red[1][wv] = q;
  }
  __syncthreads();
  s = red[0][0] + red[0][1] + red[0][2] + red[0][3];
  q = red[1][0] + red[1][1] + red[1][2] + red[1][3];
  const float mu = s * (1.f / 1024.f);
  const float var = q * (1.f / 1024.f) - mu * mu;
  const float rstd = rsqrtf(var + 1e-5f);
  const float4 gv = *(const float4*)&g[c];
  const float4 bev = *(const float4*)&be[c];
  const float o0 = (v0 - mu) * rstd * gv.x + bev.x;
  const float o1 = (v1 - mu) * rstd * gv.y + bev.y;
  const float o2 = (v2 - mu) * rstd * gv.z + bev.z;
  const float o3 = (v3 - mu) * rstd * gv.w + bev.w;
  uintx2 ov;
  ov[0] = (u32)f2bf(o0) | ((u32)f2bf(o1) << 16);
  ov[1] = (u32)f2bf(o2) | ((u32)f2bf(o3) << 16);
  *(uintx2*)&o[(size_t)row * ldo + c] = ov;
}

// ---------------------------------------------------------------------------
// out: out[m][f] = h[m][:] . outW[:][f] + outb[f], f<9. One wave per row. fp32 out.
// ---------------------------------------------------------------------------
__launch_bounds__(256)
__global__ void out_kernel(const u16* __restrict__ h, const float* __restrict__ W,
                           const float* __restrict__ bias, float* __restrict__ out) {
  const int m = blockIdx.x * 4 + (threadIdx.x >> 6);
  const int lane = threadIdx.x & 63;
  float acc[9];
#pragma unroll
  for (int f = 0; f < 9; ++f) acc[f] = 0.f;
  const u16* hr = h + (size_t)m * 1024;
#pragma unroll 4
  for (int j = 0; j < 16; ++j) {
    const int k = lane + j * 64;
    const float hv = bf2f(hr[k]);
    const float* wr = W + (size_t)k * 9;
#pragma unroll
    for (int f = 0; f < 9; ++f) acc[f] += hv * wr[f];
  }
#pragma unroll
  for (int f = 0; f < 9; ++f)
#pragma unroll
    for (int mm = 32; mm; mm >>= 1) acc[f] += __shfl_xor(acc[f], mm);
  if (lane < 9) out[(size_t)m * 9 + lane] = acc[lane] + bias[lane];
}

// ---------------------------------------------------------------------------
extern "C" void kernel_launch(void* const* d_in, const int* in_sizes, int n_in,
                              void* d_out, int out_size, void* d_ws, size_t ws_size,
                              hipStream_t stream) {
  (void)in_sizes; (void)n_in; (void)out_size; (void)ws_size;
  const float* x     = (const float*)d_in[0];
  const float* encW  = (const float*)d_in[1];
  const float* encB  = (const float*)d_in[2];
  const float* Wq    = (const float*)d_in[3];
  const float* bq    = (const float*)d_in[4];
  const float* Wk    = (const float*)d_in[5];
  const float* bk    = (const float*)d_in[6];
  const float* Wv    = (const float*)d_in[7];
  const float* bv    = (const float*)d_in[8];
  const float* Wo    = (const float*)d_in[9];
  const float* bo    = (const float*)d_in[10];
  const float* W1    = (const float*)d_in[11];
  const float* b1    = (const float*)d_in[12];
  const float* W2    = (const float*)d_in[13];
  const float* b2    = (const float*)d_in[14];
  const float* ln1w  = (const float*)d_in[15];
  const float* ln1b  = (const float*)d_in[16];
  const float* ln2w  = (const float*)d_in[17];
  const float* ln2b  = (const float*)d_in[18];
  const float* outW  = (const float*)d_in[19];
  const float* outB  = (const float*)d_in[20];
  float* out = (float*)d_out;

  char* ws = (char*)d_ws;
  size_t off = 0;
  auto alloc = [&](size_t bytes) -> void* {
    void* p = ws + off;
    off += (bytes + 255) & ~(size_t)255;
    return p;
  };
  u16* h    = (u16*)alloc(19660800ull * 2);   // [19200][1024]
  u16* qkv  = (u16*)alloc(58982400ull * 2);   // [19200][3072]
  u16* abuf = (u16*)alloc(19660800ull * 2);   // ctx flat [19200][1024]
  u16* Bqkv = (u16*)alloc(6291456ull * 2);    // [2][3072][1024]
  u16* Bwo  = (u16*)alloc(2097152ull * 2);    // [2][1024][1024] transposed
  u16* Bw1  = (u16*)alloc(2097152ull * 2);
  u16* Bw2  = (u16*)alloc(2097152ull * 2);
  float* bqkv = (float*)alloc(6144ull * 4);   // [2][3072] fp32
  // column-slot aliases inside qkv (stride 3072), reusing dead q/k/v slots:
  u16* ybuf = qkv;          // q-slot: Wo-gemm output (q dead after attention)
  u16* x1   = qkv + 1024;   // k-slot: ln1 output
  u16* mid  = qkv + 2048;   // v-slot: fc2/ELU output
  u16* y2   = abuf;         // dense: fc1 output (+x1 residual); abuf dead by then

  pack_qkv_t<<<dim3(16, 32), 256, 0, stream>>>(Wq, Bqkv);
  pack_qkv_t<<<dim3(16, 32), 256, 0, stream>>>(Wk, Bqkv + 1048576);
  pack_qkv_t<<<dim3(16, 32), 256, 0, stream>>>(Wv, Bqkv + 2097152);
  pack_sq_t<<<dim3(256, 2), 256, 0, stream>>>(Wo, Bwo);
  pack_sq_t<<<dim3(256, 2), 256, 0, stream>>>(W1, Bw1);
  pack_sq_t<<<dim3(256, 2), 256, 0, stream>>>(W2, Bw2);
  pack_bias<<<24, 256, 0, stream>>>(bq, bk, bv, bqkv);
  enc_kernel<<<76800, 256, 0, stream>>>(x, encW, encB, h);

  for (int l = 0; l < 2; ++l) {
    gemm_bt_wide<<<dim3(12, 150), 512, 0, stream>>>(
        h, 1024, Bqkv + (size_t)l * 3145728, bqkv + l * 3072, qkv, 3072);
    attn_mfma<<<dim3(10, 512), 256, 0, stream>>>(qkv, abuf);
    gemm_bt<1><<<dim3(8, 150), 256, 0, stream>>>(
        abuf, 1024, Bwo + (size_t)l * 1048576, bo + l * 1024, h, 1024, ybuf, 3072);
    ln_kernel<<<19200, 256, 0, stream>>>(ybuf, 3072, ln1w + l * 1024, ln1b + l * 1024, x1, 3072);
    gemm_bt<2><<<dim3(8, 150), 256, 0, stream>>>(
        x1, 3072, Bw2 + (size_t)l * 1048576, b2 + l * 1024, nullptr, 0, mid, 3072);
    gemm_bt<1><<<dim3(8, 150), 256, 0, stream>>>(
        mid, 3072, Bw1 + (size_t)l * 1048576, b1 + l * 1024, x1, 3072, y2, 1024);
    ln_kernel<<<19200, 256, 0, stream>>>(y2, 1024, ln2w + l * 1024, ln2b + l * 1024, h, 1024);
  }
  out_kernel<<<4800, 256, 0, stream>>>(h, outW, outB, out);
}

// Round 10
// 1287.703 us; speedup vs baseline: 1.2181x; 1.0304x over previous
//
#include <hip/hip_runtime.h>

typedef unsigned short u16;
typedef unsigned int u32;
typedef __attribute__((ext_vector_type(8))) short shortx8;
typedef __attribute__((ext_vector_type(4))) float floatx4;
typedef __attribute__((ext_vector_type(4))) u32 uintx4;
typedef __attribute__((ext_vector_type(2))) u32 uintx2;

#define AS1 __attribute__((address_space(1)))
#define AS3 __attribute__((address_space(3)))

__device__ __forceinline__ float bf2f(u16 u) {
  return __builtin_bit_cast(float, ((u32)u) << 16);
}
__device__ __forceinline__ u16 f2bf(float f) {
  u32 i = __builtin_bit_cast(u32, f);
  u32 r = (i + 0x7fffu + ((i >> 16) & 1u)) >> 16;  // RNE
  return (u16)r;
}

// ---------------------------------------------------------------------------
// Coalesced packing: 64x64 LDS-tile transpose, fp32 -> bf16. (r7, measured-good)
// ---------------------------------------------------------------------------
__launch_bounds__(256)
__global__ void pack_qkv_t(const float* __restrict__ W, u16* __restrict__ dst) {
  __shared__ u16 T[64][72];
  const int kt = blockIdx.x, y = blockIdx.y;
  const int l = y >> 4, h = y & 15;
  const int t = threadIdx.x;
  const int rr = t >> 2, cq = (t & 3) * 16;
  const float* src = W + ((size_t)y * 1024 + kt * 64 + rr) * 64 + cq;
#pragma unroll
  for (int e4 = 0; e4 < 4; ++e4) {
    float4 f = *(const float4*)(src + e4 * 4);
    T[cq + e4 * 4 + 0][rr] = f2bf(f.x);
    T[cq + e4 * 4 + 1][rr] = f2bf(f.y);
    T[cq + e4 * 4 + 2][rr] = f2bf(f.z);
    T[cq + e4 * 4 + 3][rr] = f2bf(f.w);
  }
  __syncthreads();
  const int dd = t >> 2, kq = (t & 3) * 16;
  u16* drow = dst + (size_t)l * 3145728 + ((size_t)h * 64 + dd) * 1024 + kt * 64 + kq;
  *(uintx4*)(drow) = *(const uintx4*)&T[dd][kq];
  *(uintx4*)(drow + 8) = *(const uintx4*)&T[dd][kq + 8];
}

__launch_bounds__(256)
__global__ void pack_sq_t(const float* __restrict__ W, u16* __restrict__ dst) {
  __shared__ u16 T[64][72];
  const int ct = blockIdx.x & 15, rt = blockIdx.x >> 4, l = blockIdx.y;
  const int t = threadIdx.x;
  const int rr = t >> 2, cq = (t & 3) * 16;
  const float* src = W + (size_t)l * 1048576 + (size_t)(rt * 64 + rr) * 1024 + ct * 64 + cq;
#pragma unroll
  for (int e4 = 0; e4 < 4; ++e4) {
    float4 f = *(const float4*)(src + e4 * 4);
    T[cq + e4 * 4 + 0][rr] = f2bf(f.x);
    T[cq + e4 * 4 + 1][rr] = f2bf(f.y);
    T[cq + e4 * 4 + 2][rr] = f2bf(f.z);
    T[cq + e4 * 4 + 3][rr] = f2bf(f.w);
  }
  __syncthreads();
  const int cc = t >> 2, rq = (t & 3) * 16;
  u16* drow = dst + (size_t)l * 1048576 + (size_t)(ct * 64 + cc) * 1024 + rt * 64 + rq;
  *(uintx4*)(drow) = *(const uintx4*)&T[cc][rq];
  *(uintx4*)(drow + 8) = *(const uintx4*)&T[cc][rq + 8];
}

// ---------------------------------------------------------------------------
// Wo pack with head-interleave permutation absorbed:
// dst[l][n][k'] = Wo[l][i][n] where i = d*16+h and k' = h*64+d.
// Tile: r-rows [rt*64, rt*64+64) x n-cols [nt*64, nt*64+64). d0 = rt*4.
// ---------------------------------------------------------------------------
__launch_bounds__(256)
__global__ void pack_wo_t(const float* __restrict__ W, u16* __restrict__ dst) {
  __shared__ u16 T[64][72];  // T[n_local][rr]
  const int rt = blockIdx.x >> 4, nt = blockIdx.x & 15, l = blockIdx.y;
  const int t = threadIdx.x;
  const int rr = t >> 2, cq = (t & 3) * 16;
  const float* src = W + (size_t)l * 1048576 + (size_t)(rt * 64 + rr) * 1024 + nt * 64 + cq;
#pragma unroll
  for (int e4 = 0; e4 < 4; ++e4) {
    float4 f = *(const float4*)(src + e4 * 4);
    T[cq + e4 * 4 + 0][rr] = f2bf(f.x);
    T[cq + e4 * 4 + 1][rr] = f2bf(f.y);
    T[cq + e4 * 4 + 2][rr] = f2bf(f.z);
    T[cq + e4 * 4 + 3][rr] = f2bf(f.w);
  }
  __syncthreads();
  // write: 4 passes of (16 n_local x 16 h); rr = dd*16 + hh -> k' = hh*64 + rt*4 + dd
  const int hh = t & 15;
#pragma unroll
  for (int pass = 0; pass < 4; ++pass) {
    const int nl = pass * 16 + (t >> 4);
    uintx2 pk;
    u16 v0 = T[nl][0 * 16 + hh], v1 = T[nl][1 * 16 + hh];
    u16 v2 = T[nl][2 * 16 + hh], v3 = T[nl][3 * 16 + hh];
    pk[0] = (u32)v0 | ((u32)v1 << 16);
    pk[1] = (u32)v2 | ((u32)v3 << 16);
    *(uintx2*)&dst[(size_t)l * 1048576 + (size_t)(nt * 64 + nl) * 1024 + hh * 64 + rt * 4] = pk;
  }
}

__launch_bounds__(256)
__global__ void pack_bias(const float* __restrict__ bq, const float* __restrict__ bk,
                          const float* __restrict__ bv, float* __restrict__ bias) {
  const int i = blockIdx.x * 256 + threadIdx.x;  // [0, 6144)
  const int l = i / 3072, n = i % 3072;
  const int which = n >> 10, nn = n & 1023;
  const float* s = (which == 0) ? bq : (which == 1) ? bk : bv;
  bias[i] = s[l * 1024 + nn];
}

// ---------------------------------------------------------------------------
// enc_in: h[m][n] = x[m][:9] @ W[:9][n] + b[n]   (fp32 in, bf16 out)
// ---------------------------------------------------------------------------
__launch_bounds__(256)
__global__ void enc_kernel(const float* __restrict__ x, const float* __restrict__ W,
                           const float* __restrict__ bias, u16* __restrict__ h) {
  const size_t i = (size_t)blockIdx.x * 256 + threadIdx.x;  // 19200*1024
  const int m = (int)(i >> 10), n = (int)(i & 1023);
  const float* xr = x + (size_t)m * 9;
  float acc = bias[n];
#pragma unroll
  for (int f = 0; f < 9; ++f) acc += xr[f] * W[f * 1024 + n];
  h[i] = f2bf(acc);
}

// ---------------------------------------------------------------------------
// GEMM (r6-exact, proven): 128x128 tile, BK=64, 4 waves, single-buffer.
// EPI: 0 = bias; 1 = bias + residual R; 2 = bias + ELU
// ---------------------------------------------------------------------------
template <int EPI>
__launch_bounds__(256)
__global__ void gemm_bt(const u16* __restrict__ A, int lda,
                        const u16* __restrict__ Bt,
                        const float* __restrict__ bias,
                        const u16* __restrict__ R, int ldr,
                        u16* __restrict__ C, int ldc) {
  constexpr int K = 1024;
  __shared__ u16 As[128 * 64];
  __shared__ u16 Bs[128 * 64];
  const int tid = threadIdx.x;
  const int lane = tid & 63;
  const int w = tid >> 6;
  const int wr = w >> 1, wc = w & 1;
  const int m0 = blockIdx.y * 128, n0 = blockIdx.x * 128;

  floatx4 acc[4][4];
#pragma unroll
  for (int i = 0; i < 4; ++i)
#pragma unroll
    for (int j = 0; j < 4; ++j) acc[i][j] = (floatx4){0.f, 0.f, 0.f, 0.f};

  const u16* Ab = A + (size_t)m0 * lda;
  const u16* Bb = Bt + (size_t)n0 * K;

  for (int k0 = 0; k0 < K; k0 += 64) {
#pragma unroll
    for (int p = 0; p < 4; ++p) {
      const int o = p * 4096 + tid * 16;
      const int row = o >> 7;
      const int ke = (o & 127) >> 1;
      __builtin_amdgcn_global_load_lds((const AS1 void*)(Ab + (size_t)row * lda + (k0 + ke)),
                                       (AS3 void*)((char*)As + o), 16, 0, 0);
      __builtin_amdgcn_global_load_lds((const AS1 void*)(Bb + (size_t)row * K + (k0 + ke)),
                                       (AS3 void*)((char*)Bs + o), 16, 0, 0);
    }
    __syncthreads();
#pragma unroll
    for (int ks = 0; ks < 2; ++ks) {
      shortx8 af[4], bfr[4];
#pragma unroll
      for (int i = 0; i < 4; ++i) {
        const int ar = wr * 64 + i * 16 + (lane & 15);
        af[i] = *(const shortx8*)&As[ar * 64 + ks * 32 + (lane >> 4) * 8];
        const int br = wc * 64 + i * 16 + (lane & 15);
        bfr[i] = *(const shortx8*)&Bs[br * 64 + ks * 32 + (lane >> 4) * 8];
      }
#pragma unroll
      for (int i = 0; i < 4; ++i)
#pragma unroll
        for (int j = 0; j < 4; ++j)
          acc[i][j] = __builtin_amdgcn_mfma_f32_16x16x32_bf16(af[i], bfr[j], acc[i][j], 0, 0, 0);
    }
    __syncthreads();
  }

  const int lr = (lane >> 4) * 4, lc = lane & 15;
#pragma unroll
  for (int i = 0; i < 4; ++i) {
#pragma unroll
    for (int j = 0; j < 4; ++j) {
      const int col = n0 + wc * 64 + j * 16 + lc;
      const float bv = bias[col];
#pragma unroll
      for (int r = 0; r < 4; ++r) {
        const int row = m0 + wr * 64 + i * 16 + lr + r;
        float v = acc[i][j][r] + bv;
        if (EPI == 1) v += bf2f(R[(size_t)row * ldr + col]);
        if (EPI == 2) v = v > 0.f ? v : expm1f(v);
        C[(size_t)row * ldc + col] = f2bf(v);
      }
    }
  }
}

// ---------------------------------------------------------------------------
// WIDE GEMM for QKV (r9-proven): 128x256 tile, 8 waves, single-buffer.
// ---------------------------------------------------------------------------
__launch_bounds__(512)
__global__ void gemm_bt_wide(const u16* __restrict__ A, int lda,
                             const u16* __restrict__ Bt,
                             const float* __restrict__ bias,
                             u16* __restrict__ C, int ldc) {
  constexpr int K = 1024;
  __shared__ u16 As[128 * 64];
  __shared__ u16 Bs[256 * 64];
  const int tid = threadIdx.x;
  const int lane = tid & 63;
  const int w = tid >> 6;
  const int wr = w >> 2, wc = w & 3;
  const int m0 = blockIdx.y * 128, n0 = blockIdx.x * 256;

  floatx4 acc[4][4];
#pragma unroll
  for (int i = 0; i < 4; ++i)
#pragma unroll
    for (int j = 0; j < 4; ++j) acc[i][j] = (floatx4){0.f, 0.f, 0.f, 0.f};

  const u16* Ab = A + (size_t)m0 * lda;
  const u16* Bb = Bt + (size_t)n0 * K;

  for (int k0 = 0; k0 < K; k0 += 64) {
#pragma unroll
    for (int p = 0; p < 2; ++p) {
      const int o = p * 8192 + tid * 16;
      const int row = o >> 7;
      const int ke = (o & 127) >> 1;
      __builtin_amdgcn_global_load_lds((const AS1 void*)(Ab + (size_t)row * lda + (k0 + ke)),
                                       (AS3 void*)((char*)As + o), 16, 0, 0);
    }
#pragma unroll
    for (int p = 0; p < 4; ++p) {
      const int o = p * 8192 + tid * 16;
      const int row = o >> 7;
      const int ke = (o & 127) >> 1;
      __builtin_amdgcn_global_load_lds((const AS1 void*)(Bb + (size_t)row * K + (k0 + ke)),
                                       (AS3 void*)((char*)Bs + o), 16, 0, 0);
    }
    __syncthreads();
#pragma unroll
    for (int ks = 0; ks < 2; ++ks) {
      shortx8 af[4], bfr[4];
#pragma unroll
      for (int i = 0; i < 4; ++i) {
        const int ar = wr * 64 + i * 16 + (lane & 15);
        af[i] = *(const shortx8*)&As[ar * 64 + ks * 32 + (lane >> 4) * 8];
        const int br = wc * 64 + i * 16 + (lane & 15);
        bfr[i] = *(const shortx8*)&Bs[br * 64 + ks * 32 + (lane >> 4) * 8];
      }
#pragma unroll
      for (int i = 0; i < 4; ++i)
#pragma unroll
        for (int j = 0; j < 4; ++j)
          acc[i][j] = __builtin_amdgcn_mfma_f32_16x16x32_bf16(af[i], bfr[j], acc[i][j], 0, 0, 0);
    }
    __syncthreads();
  }

  const int lr = (lane >> 4) * 4, lc = lane & 15;
#pragma unroll
  for (int i = 0; i < 4; ++i) {
#pragma unroll
    for (int j = 0; j < 4; ++j) {
      const int col = n0 + wc * 64 + j * 16 + lc;
      const float bv = bias[col];
#pragma unroll
      for (int r = 0; r < 4; ++r) {
        const int row = m0 + wr * 64 + i * 16 + lr + r;
        C[(size_t)row * ldc + col] = f2bf(acc[i][j][r] + bv);
      }
    }
  }
}

// ---------------------------------------------------------------------------
// MFMA flash attention, QBLK=128: 4 waves, each wave owns 32 q-rows processed
// as two 16-row subtiles (sequential, reusing S regs + wave-private P_ld).
// grid (5, 512). K/V staged once per 128-t chunk — half the re-fetch of r6.
// Output CONTIGUOUS ctx[b][s][h*64+d] (head-permutation absorbed in Wo pack).
// ---------------------------------------------------------------------------
__launch_bounds__(256)
__global__ void attn_mfma(const u16* __restrict__ qkv, u16* __restrict__ aout) {
  const int qt = blockIdx.x, bh = blockIdx.y;
  const int b = bh >> 4, h = bh & 15;
  const int tid = threadIdx.x, lane = tid & 63, w = tid >> 6;
  const int g = lane >> 4, lq = lane & 15;

  __shared__ u16 K_ld[128 * 72];
  __shared__ u16 Vt[64 * 136];
  __shared__ u16 P_ld[4][16 * 136];

  const size_t bbase = (size_t)b * 600 * 3072;
  const int q0 = qt * 128 + w * 32;

  shortx8 aq[2][2];
#pragma unroll
  for (int sub = 0; sub < 2; ++sub) {
    const int s = q0 + sub * 16 + lq;
    if (s < 600) {
      const u16* qp = qkv + bbase + (size_t)s * 3072 + h * 64 + g * 8;
      aq[sub][0] = *(const shortx8*)qp;
      aq[sub][1] = *(const shortx8*)(qp + 32);
    } else {
      aq[sub][0] = (shortx8){0, 0, 0, 0, 0, 0, 0, 0};
      aq[sub][1] = (shortx8){0, 0, 0, 0, 0, 0, 0, 0};
    }
  }

  floatx4 Oa[2][4];
  float m[2][4], l[2][4];
#pragma unroll
  for (int sub = 0; sub < 2; ++sub) {
#pragma unroll
    for (int db = 0; db < 4; ++db) Oa[sub][db] = (floatx4){0.f, 0.f, 0.f, 0.f};
#pragma unroll
    for (int r = 0; r < 4; ++r) { m[sub][r] = -1e30f; l[sub][r] = 0.f; }
  }

  for (int ch = 0; ch < 5; ++ch) {
    const int t0 = ch * 128;
    __syncthreads();
    {
      const int tloc = tid >> 1, dhalf = (tid & 1) * 32;
      const int tg = t0 + tloc;
      if (tg < 600) {
        const u16* kp = qkv + bbase + (size_t)tg * 3072 + 1024 + h * 64 + dhalf;
        const u16* vp = kp + 1024;
#pragma unroll
        for (int c = 0; c < 4; ++c)
          *(uintx4*)&K_ld[tloc * 72 + dhalf + c * 8] = *(const uintx4*)(kp + c * 8);
#pragma unroll
        for (int c = 0; c < 4; ++c) {
          shortx8 vv = *(const shortx8*)(vp + c * 8);
#pragma unroll
          for (int e = 0; e < 8; ++e)
            Vt[(dhalf + c * 8 + e) * 136 + tloc] = (u16)vv[e];
        }
      } else {
        const uintx4 z4 = (uintx4){0, 0, 0, 0};
#pragma unroll
        for (int c = 0; c < 4; ++c)
          *(uintx4*)&K_ld[tloc * 72 + dhalf + c * 8] = z4;
#pragma unroll
        for (int c = 0; c < 4; ++c)
#pragma unroll
          for (int e = 0; e < 8; ++e)
            Vt[(dhalf + c * 8 + e) * 136 + tloc] = 0;
      }
    }
    __syncthreads();

#pragma unroll
    for (int sub = 0; sub < 2; ++sub) {
      floatx4 S[8];
#pragma unroll
      for (int jb = 0; jb < 8; ++jb) {
        S[jb] = (floatx4){0.f, 0.f, 0.f, 0.f};
#pragma unroll
        for (int ks = 0; ks < 2; ++ks) {
          shortx8 bk = *(const shortx8*)&K_ld[(jb * 16 + lq) * 72 + ks * 32 + g * 8];
          S[jb] = __builtin_amdgcn_mfma_f32_16x16x32_bf16(aq[sub][ks], bk, S[jb], 0, 0, 0);
        }
      }
#pragma unroll
      for (int jb = 0; jb < 8; ++jb) {
        const int tg = t0 + jb * 16 + lq;
        const bool ok = tg < 600;
#pragma unroll
        for (int r = 0; r < 4; ++r) S[jb][r] = ok ? S[jb][r] * 0.125f : -1e30f;
      }

      float scale[4];
#pragma unroll
      for (int r = 0; r < 4; ++r) {
        float v = S[0][r];
#pragma unroll
        for (int jb = 1; jb < 8; ++jb) v = fmaxf(v, S[jb][r]);
        v = fmaxf(v, __shfl_xor(v, 1));
        v = fmaxf(v, __shfl_xor(v, 2));
        v = fmaxf(v, __shfl_xor(v, 4));
        v = fmaxf(v, __shfl_xor(v, 8));
        const float mn = fmaxf(m[sub][r], v);
        scale[r] = __expf(m[sub][r] - mn);
        m[sub][r] = mn;
        l[sub][r] *= scale[r];
      }
#pragma unroll
      for (int db = 0; db < 4; ++db)
#pragma unroll
        for (int r = 0; r < 4; ++r) Oa[sub][db][r] *= scale[r];

      float sums[4] = {0.f, 0.f, 0.f, 0.f};
#pragma unroll
      for (int jb = 0; jb < 8; ++jb)
#pragma unroll
        for (int r = 0; r < 4; ++r) {
          const float p = __expf(S[jb][r] - m[sub][r]);
          sums[r] += p;
          P_ld[w][(g * 4 + r) * 136 + jb * 16 + lq] = f2bf(p);
        }
#pragma unroll
      for (int r = 0; r < 4; ++r) {
        float v = sums[r];
        v += __shfl_xor(v, 1);
        v += __shfl_xor(v, 2);
        v += __shfl_xor(v, 4);
        v += __shfl_xor(v, 8);
        l[sub][r] += v;
      }

#pragma unroll
      for (int ks = 0; ks < 4; ++ks) {
        shortx8 ap = *(const shortx8*)&P_ld[w][lq * 136 + ks * 32 + g * 8];
#pragma unroll
        for (int db = 0; db < 4; ++db) {
          shortx8 bv = *(const shortx8*)&Vt[(db * 16 + lq) * 136 + ks * 32 + g * 8];
          Oa[sub][db] = __builtin_amdgcn_mfma_f32_16x16x32_bf16(ap, bv, Oa[sub][db], 0, 0, 0);
        }
      }
    }
  }

  // epilogue: contiguous ctx[b][s][h*64 + d], d = db*16 + lq
#pragma unroll
  for (int sub = 0; sub < 2; ++sub) {
#pragma unroll
    for (int r = 0; r < 4; ++r) {
      const int sg = q0 + sub * 16 + g * 4 + r;
      if (sg < 600) {
        const float inv = 1.f / l[sub][r];
        u16* orow = aout + ((size_t)(b * 600 + sg)) * 1024 + h * 64;
#pragma unroll
        for (int db = 0; db < 4; ++db)
          orow[db * 16 + lq] = f2bf(Oa[sub][db][r] * inv);
      }
    }
  }
}

// ---------------------------------------------------------------------------
// LayerNorm over 1024 (strided rows): one block per row, biased var, eps 1e-5.
// ---------------------------------------------------------------------------
__launch_bounds__(256)
__global__ void ln_kernel(const u16* __restrict__ y, int ldy,
                          const float* __restrict__ g, const float* __restrict__ be,
                          u16* __restrict__ o, int ldo) {
  const int row = blockIdx.x, tid = threadIdx.x;
  const int lane = tid & 63, wv = tid >> 6;
  const u16* yr = y + (size_t)row * ldy;
  const int c = tid * 4;
  const uintx2 yv = *(const uintx2*)&yr[c];
  float v0 = bf2f((u16)(yv[0] & 0xffffu)), v1 = bf2f((u16)(yv[0] >> 16));
  float v2 = bf2f((u16)(yv[1] & 0xffffu)), v3 = bf2f((u16)(yv[1] >> 16));
  float s = v0 + v1 + v2 + v3;
  float q = v0 * v0 + v1 * v1 + v2 * v2 + v3 * v3;
#pragma unroll
  for (int m = 32; m; m >>= 1) {
    s += __shfl_xor(s, m);
    q += __shfl_xor(q, m);
  }
  __shared__ float red[2][4];
  if (lane == 0) {
    red[0][wv] = s;
    red[1][wv] = q;
  }
  __syncthreads();
  s = red[0][0] + red[0][1] + red[0][2] + red[0][3];
  q = red[1][0] + red[1][1] + red[1][2] + red[1][3];
  const float mu = s * (1.f / 1024.f);
  const float var = q * (1.f / 1024.f) - mu * mu;
  const float rstd = rsqrtf(var + 1e-5f);
  const float4 gv = *(const float4*)&g[c];
  const float4 bev = *(const float4*)&be[c];
  const float o0 = (v0 - mu) * rstd * gv.x + bev.x;
  const float o1 = (v1 - mu) * rstd * gv.y + bev.y;
  const float o2 = (v2 - mu) * rstd * gv.z + bev.z;
  const float o3 = (v3 - mu) * rstd * gv.w + bev.w;
  uintx2 ov;
  ov[0] = (u32)f2bf(o0) | ((u32)f2bf(o1) << 16);
  ov[1] = (u32)f2bf(o2) | ((u32)f2bf(o3) << 16);
  *(uintx2*)&o[(size_t)row * ldo + c] = ov;
}

// ---------------------------------------------------------------------------
// out: out[m][f] = h[m][:] . outW[:][f] + outb[f], f<9. One wave per row. fp32 out.
// ---------------------------------------------------------------------------
__launch_bounds__(256)
__global__ void out_kernel(const u16* __restrict__ h, const float* __restrict__ W,
                           const float* __restrict__ bias, float* __restrict__ out) {
  const int m = blockIdx.x * 4 + (threadIdx.x >> 6);
  const int lane = threadIdx.x & 63;
  float acc[9];
#pragma unroll
  for (int f = 0; f < 9; ++f) acc[f] = 0.f;
  const u16* hr = h + (size_t)m * 1024;
#pragma unroll 4
  for (int j = 0; j < 16; ++j) {
    const int k = lane + j * 64;
    const float hv = bf2f(hr[k]);
    const float* wr = W + (size_t)k * 9;
#pragma unroll
    for (int f = 0; f < 9; ++f) acc[f] += hv * wr[f];
  }
#pragma unroll
  for (int f = 0; f < 9; ++f)
#pragma unroll
    for (int mm = 32; mm; mm >>= 1) acc[f] += __shfl_xor(acc[f], mm);
  if (lane < 9) out[(size_t)m * 9 + lane] = acc[lane] + bias[lane];
}

// ---------------------------------------------------------------------------
extern "C" void kernel_launch(void* const* d_in, const int* in_sizes, int n_in,
                              void* d_out, int out_size, void* d_ws, size_t ws_size,
                              hipStream_t stream) {
  (void)in_sizes; (void)n_in; (void)out_size; (void)ws_size;
  const float* x     = (const float*)d_in[0];
  const float* encW  = (const float*)d_in[1];
  const float* encB  = (const float*)d_in[2];
  const float* Wq    = (const float*)d_in[3];
  const float* bq    = (const float*)d_in[4];
  const float* Wk    = (const float*)d_in[5];
  const float* bk    = (const float*)d_in[6];
  const float* Wv    = (const float*)d_in[7];
  const float* bv    = (const float*)d_in[8];
  const float* Wo    = (const float*)d_in[9];
  const float* bo    = (const float*)d_in[10];
  const float* W1    = (const float*)d_in[11];
  const float* b1    = (const float*)d_in[12];
  const float* W2    = (const float*)d_in[13];
  const float* b2    = (const float*)d_in[14];
  const float* ln1w  = (const float*)d_in[15];
  const float* ln1b  = (const float*)d_in[16];
  const float* ln2w  = (const float*)d_in[17];
  const float* ln2b  = (const float*)d_in[18];
  const float* outW  = (const float*)d_in[19];
  const float* outB  = (const float*)d_in[20];
  float* out = (float*)d_out;

  char* ws = (char*)d_ws;
  size_t off = 0;
  auto alloc = [&](size_t bytes) -> void* {
    void* p = ws + off;
    off += (bytes + 255) & ~(size_t)255;
    return p;
  };
  u16* h    = (u16*)alloc(19660800ull * 2);   // [19200][1024]
  u16* qkv  = (u16*)alloc(58982400ull * 2);   // [19200][3072]
  u16* abuf = (u16*)alloc(19660800ull * 2);   // ctx [19200][1024] (h*64+d layout)
  u16* Bqkv = (u16*)alloc(6291456ull * 2);    // [2][3072][1024]
  u16* Bwo  = (u16*)alloc(2097152ull * 2);    // [2][1024][1024] permuted-transposed
  u16* Bw1  = (u16*)alloc(2097152ull * 2);
  u16* Bw2  = (u16*)alloc(2097152ull * 2);
  float* bqkv = (float*)alloc(6144ull * 4);   // [2][3072] fp32
  // column-slot aliases inside qkv (stride 3072), reusing dead q/k/v slots:
  u16* ybuf = qkv;          // q-slot: Wo-gemm output (q dead after attention)
  u16* x1   = qkv + 1024;   // k-slot: ln1 output
  u16* mid  = qkv + 2048;   // v-slot: fc2/ELU output
  u16* y2   = abuf;         // dense: fc1 output (+x1 residual); abuf dead by then

  pack_qkv_t<<<dim3(16, 32), 256, 0, stream>>>(Wq, Bqkv);
  pack_qkv_t<<<dim3(16, 32), 256, 0, stream>>>(Wk, Bqkv + 1048576);
  pack_qkv_t<<<dim3(16, 32), 256, 0, stream>>>(Wv, Bqkv + 2097152);
  pack_wo_t<<<dim3(256, 2), 256, 0, stream>>>(Wo, Bwo);
  pack_sq_t<<<dim3(256, 2), 256, 0, stream>>>(W1, Bw1);
  pack_sq_t<<<dim3(256, 2), 256, 0, stream>>>(W2, Bw2);
  pack_bias<<<24, 256, 0, stream>>>(bq, bk, bv, bqkv);
  enc_kernel<<<76800, 256, 0, stream>>>(x, encW, encB, h);

  for (int l = 0; l < 2; ++l) {
    gemm_bt_wide<<<dim3(12, 150), 512, 0, stream>>>(
        h, 1024, Bqkv + (size_t)l * 3145728, bqkv + l * 3072, qkv, 3072);
    attn_mfma<<<dim3(5, 512), 256, 0, stream>>>(qkv, abuf);
    gemm_bt<1><<<dim3(8, 150), 256, 0, stream>>>(
        abuf, 1024, Bwo + (size_t)l * 1048576, bo + l * 1024, h, 1024, ybuf, 3072);
    ln_kernel<<<19200, 256, 0, stream>>>(ybuf, 3072, ln1w + l * 1024, ln1b + l * 1024, x1, 3072);
    gemm_bt<2><<<dim3(8, 150), 256, 0, stream>>>(
        x1, 3072, Bw2 + (size_t)l * 1048576, b2 + l * 1024, nullptr, 0, mid, 3072);
    gemm_bt<1><<<dim3(8, 150), 256, 0, stream>>>(
        mid, 3072, Bw1 + (size_t)l * 1048576, b1 + l * 1024, x1, 3072, y2, 1024);
    ln_kernel<<<19200, 256, 0, stream>>>(y2, 1024, ln2w + l * 1024, ln2b + l * 1024, h, 1024);
  }
  out_kernel<<<4800, 256, 0, stream>>>(h, outW, outB, out);
}

// Round 11
// 1253.692 us; speedup vs baseline: 1.2512x; 1.0271x over previous
//
#include <hip/hip_runtime.h>

typedef unsigned short u16;
typedef unsigned int u32;
typedef __attribute__((ext_vector_type(8))) short shortx8;
typedef __attribute__((ext_vector_type(4))) float floatx4;
typedef __attribute__((ext_vector_type(4))) u32 uintx4;
typedef __attribute__((ext_vector_type(2))) u32 uintx2;

#define AS1 __attribute__((address_space(1)))
#define AS3 __attribute__((address_space(3)))

__device__ __forceinline__ float bf2f(u16 u) {
  return __builtin_bit_cast(float, ((u32)u) << 16);
}
__device__ __forceinline__ u16 f2bf(float f) {
  u32 i = __builtin_bit_cast(u32, f);
  u32 r = (i + 0x7fffu + ((i >> 16) & 1u)) >> 16;  // RNE
  return (u16)r;
}

// ---------------------------------------------------------------------------
// Coalesced packing: 64x64 LDS-tile transpose, fp32 -> bf16. (r7, measured-good)
// ---------------------------------------------------------------------------
__launch_bounds__(256)
__global__ void pack_qkv_t(const float* __restrict__ W, u16* __restrict__ dst) {
  __shared__ u16 T[64][72];
  const int kt = blockIdx.x, y = blockIdx.y;
  const int l = y >> 4, h = y & 15;
  const int t = threadIdx.x;
  const int rr = t >> 2, cq = (t & 3) * 16;
  const float* src = W + ((size_t)y * 1024 + kt * 64 + rr) * 64 + cq;
#pragma unroll
  for (int e4 = 0; e4 < 4; ++e4) {
    float4 f = *(const float4*)(src + e4 * 4);
    T[cq + e4 * 4 + 0][rr] = f2bf(f.x);
    T[cq + e4 * 4 + 1][rr] = f2bf(f.y);
    T[cq + e4 * 4 + 2][rr] = f2bf(f.z);
    T[cq + e4 * 4 + 3][rr] = f2bf(f.w);
  }
  __syncthreads();
  const int dd = t >> 2, kq = (t & 3) * 16;
  u16* drow = dst + (size_t)l * 3145728 + ((size_t)h * 64 + dd) * 1024 + kt * 64 + kq;
  *(uintx4*)(drow) = *(const uintx4*)&T[dd][kq];
  *(uintx4*)(drow + 8) = *(const uintx4*)&T[dd][kq + 8];
}

__launch_bounds__(256)
__global__ void pack_sq_t(const float* __restrict__ W, u16* __restrict__ dst) {
  __shared__ u16 T[64][72];
  const int ct = blockIdx.x & 15, rt = blockIdx.x >> 4, l = blockIdx.y;
  const int t = threadIdx.x;
  const int rr = t >> 2, cq = (t & 3) * 16;
  const float* src = W + (size_t)l * 1048576 + (size_t)(rt * 64 + rr) * 1024 + ct * 64 + cq;
#pragma unroll
  for (int e4 = 0; e4 < 4; ++e4) {
    float4 f = *(const float4*)(src + e4 * 4);
    T[cq + e4 * 4 + 0][rr] = f2bf(f.x);
    T[cq + e4 * 4 + 1][rr] = f2bf(f.y);
    T[cq + e4 * 4 + 2][rr] = f2bf(f.z);
    T[cq + e4 * 4 + 3][rr] = f2bf(f.w);
  }
  __syncthreads();
  const int cc = t >> 2, rq = (t & 3) * 16;
  u16* drow = dst + (size_t)l * 1048576 + (size_t)(ct * 64 + cc) * 1024 + rt * 64 + rq;
  *(uintx4*)(drow) = *(const uintx4*)&T[cc][rq];
  *(uintx4*)(drow + 8) = *(const uintx4*)&T[cc][rq + 8];
}

// ---------------------------------------------------------------------------
// Wo pack with head-interleave permutation absorbed (r10, validated):
// dst[l][n][h*64+d] = Wo[l][d*16+h][n].
// ---------------------------------------------------------------------------
__launch_bounds__(256)
__global__ void pack_wo_t(const float* __restrict__ W, u16* __restrict__ dst) {
  __shared__ u16 T[64][72];  // T[n_local][rr]
  const int rt = blockIdx.x >> 4, nt = blockIdx.x & 15, l = blockIdx.y;
  const int t = threadIdx.x;
  const int rr = t >> 2, cq = (t & 3) * 16;
  const float* src = W + (size_t)l * 1048576 + (size_t)(rt * 64 + rr) * 1024 + nt * 64 + cq;
#pragma unroll
  for (int e4 = 0; e4 < 4; ++e4) {
    float4 f = *(const float4*)(src + e4 * 4);
    T[cq + e4 * 4 + 0][rr] = f2bf(f.x);
    T[cq + e4 * 4 + 1][rr] = f2bf(f.y);
    T[cq + e4 * 4 + 2][rr] = f2bf(f.z);
    T[cq + e4 * 4 + 3][rr] = f2bf(f.w);
  }
  __syncthreads();
  const int hh = t & 15;
#pragma unroll
  for (int pass = 0; pass < 4; ++pass) {
    const int nl = pass * 16 + (t >> 4);
    uintx2 pk;
    u16 v0 = T[nl][0 * 16 + hh], v1 = T[nl][1 * 16 + hh];
    u16 v2 = T[nl][2 * 16 + hh], v3 = T[nl][3 * 16 + hh];
    pk[0] = (u32)v0 | ((u32)v1 << 16);
    pk[1] = (u32)v2 | ((u32)v3 << 16);
    *(uintx2*)&dst[(size_t)l * 1048576 + (size_t)(nt * 64 + nl) * 1024 + hh * 64 + rt * 4] = pk;
  }
}

__launch_bounds__(256)
__global__ void pack_bias(const float* __restrict__ bq, const float* __restrict__ bk,
                          const float* __restrict__ bv, float* __restrict__ bias) {
  const int i = blockIdx.x * 256 + threadIdx.x;  // [0, 6144)
  const int l = i / 3072, n = i % 3072;
  const int which = n >> 10, nn = n & 1023;
  const float* s = (which == 0) ? bq : (which == 1) ? bk : bv;
  bias[i] = s[l * 1024 + nn];
}

// ---------------------------------------------------------------------------
// enc_in: h[m][n] = x[m][:9] @ W[:9][n] + b[n]   (fp32 in, bf16 out)
// ---------------------------------------------------------------------------
__launch_bounds__(256)
__global__ void enc_kernel(const float* __restrict__ x, const float* __restrict__ W,
                           const float* __restrict__ bias, u16* __restrict__ h) {
  const size_t i = (size_t)blockIdx.x * 256 + threadIdx.x;  // 19200*1024
  const int m = (int)(i >> 10), n = (int)(i & 1023);
  const float* xr = x + (size_t)m * 9;
  float acc = bias[n];
#pragma unroll
  for (int f = 0; f < 9; ++f) acc += xr[f] * W[f * 1024 + n];
  h[i] = f2bf(acc);
}

// ---------------------------------------------------------------------------
// WIDE GEMM (r9-proven structure): 128x256 tile, BK=64, 8 waves (2Mx4N),
// 512 threads, single-buffer, global_load_lds, direct epilogue.
// EPI: 0 = bias; 1 = bias + residual R; 2 = bias + ELU
// ---------------------------------------------------------------------------
template <int EPI>
__launch_bounds__(512)
__global__ void gemm_bt_wide(const u16* __restrict__ A, int lda,
                             const u16* __restrict__ Bt,
                             const float* __restrict__ bias,
                             const u16* __restrict__ R, int ldr,
                             u16* __restrict__ C, int ldc) {
  constexpr int K = 1024;
  __shared__ u16 As[128 * 64];
  __shared__ u16 Bs[256 * 64];
  const int tid = threadIdx.x;
  const int lane = tid & 63;
  const int w = tid >> 6;
  const int wr = w >> 2, wc = w & 3;
  const int m0 = blockIdx.y * 128, n0 = blockIdx.x * 256;

  floatx4 acc[4][4];
#pragma unroll
  for (int i = 0; i < 4; ++i)
#pragma unroll
    for (int j = 0; j < 4; ++j) acc[i][j] = (floatx4){0.f, 0.f, 0.f, 0.f};

  const u16* Ab = A + (size_t)m0 * lda;
  const u16* Bb = Bt + (size_t)n0 * K;

  for (int k0 = 0; k0 < K; k0 += 64) {
#pragma unroll
    for (int p = 0; p < 2; ++p) {
      const int o = p * 8192 + tid * 16;
      const int row = o >> 7;
      const int ke = (o & 127) >> 1;
      __builtin_amdgcn_global_load_lds((const AS1 void*)(Ab + (size_t)row * lda + (k0 + ke)),
                                       (AS3 void*)((char*)As + o), 16, 0, 0);
    }
#pragma unroll
    for (int p = 0; p < 4; ++p) {
      const int o = p * 8192 + tid * 16;
      const int row = o >> 7;
      const int ke = (o & 127) >> 1;
      __builtin_amdgcn_global_load_lds((const AS1 void*)(Bb + (size_t)row * K + (k0 + ke)),
                                       (AS3 void*)((char*)Bs + o), 16, 0, 0);
    }
    __syncthreads();
#pragma unroll
    for (int ks = 0; ks < 2; ++ks) {
      shortx8 af[4], bfr[4];
#pragma unroll
      for (int i = 0; i < 4; ++i) {
        const int ar = wr * 64 + i * 16 + (lane & 15);
        af[i] = *(const shortx8*)&As[ar * 64 + ks * 32 + (lane >> 4) * 8];
        const int br = wc * 64 + i * 16 + (lane & 15);
        bfr[i] = *(const shortx8*)&Bs[br * 64 + ks * 32 + (lane >> 4) * 8];
      }
#pragma unroll
      for (int i = 0; i < 4; ++i)
#pragma unroll
        for (int j = 0; j < 4; ++j)
          acc[i][j] = __builtin_amdgcn_mfma_f32_16x16x32_bf16(af[i], bfr[j], acc[i][j], 0, 0, 0);
    }
    __syncthreads();
  }

  const int lr = (lane >> 4) * 4, lc = lane & 15;
#pragma unroll
  for (int i = 0; i < 4; ++i) {
#pragma unroll
    for (int j = 0; j < 4; ++j) {
      const int col = n0 + wc * 64 + j * 16 + lc;
      const float bv = bias[col];
#pragma unroll
      for (int r = 0; r < 4; ++r) {
        const int row = m0 + wr * 64 + i * 16 + lr + r;
        float v = acc[i][j][r] + bv;
        if (EPI == 1) v += bf2f(R[(size_t)row * ldr + col]);
        if (EPI == 2) v = v > 0.f ? v : expm1f(v);
        C[(size_t)row * ldc + col] = f2bf(v);
      }
    }
  }
}

// ---------------------------------------------------------------------------
// MFMA flash attention (r10 structure) + T5 setprio + T13 defer-max +
// last-chunk-only masking.
// ---------------------------------------------------------------------------
__launch_bounds__(256)
__global__ void attn_mfma(const u16* __restrict__ qkv, u16* __restrict__ aout) {
  const int qt = blockIdx.x, bh = blockIdx.y;
  const int b = bh >> 4, h = bh & 15;
  const int tid = threadIdx.x, lane = tid & 63, w = tid >> 6;
  const int g = lane >> 4, lq = lane & 15;

  __shared__ u16 K_ld[128 * 72];
  __shared__ u16 Vt[64 * 136];
  __shared__ u16 P_ld[4][16 * 136];

  const size_t bbase = (size_t)b * 600 * 3072;
  const int q0 = qt * 128 + w * 32;

  shortx8 aq[2][2];
#pragma unroll
  for (int sub = 0; sub < 2; ++sub) {
    const int s = q0 + sub * 16 + lq;
    if (s < 600) {
      const u16* qp = qkv + bbase + (size_t)s * 3072 + h * 64 + g * 8;
      aq[sub][0] = *(const shortx8*)qp;
      aq[sub][1] = *(const shortx8*)(qp + 32);
    } else {
      aq[sub][0] = (shortx8){0, 0, 0, 0, 0, 0, 0, 0};
      aq[sub][1] = (shortx8){0, 0, 0, 0, 0, 0, 0, 0};
    }
  }

  floatx4 Oa[2][4];
  float m[2][4], l[2][4];
#pragma unroll
  for (int sub = 0; sub < 2; ++sub) {
#pragma unroll
    for (int db = 0; db < 4; ++db) Oa[sub][db] = (floatx4){0.f, 0.f, 0.f, 0.f};
#pragma unroll
    for (int r = 0; r < 4; ++r) { m[sub][r] = -1e30f; l[sub][r] = 0.f; }
  }

  for (int ch = 0; ch < 5; ++ch) {
    const int t0 = ch * 128;
    __syncthreads();
    {
      const int tloc = tid >> 1, dhalf = (tid & 1) * 32;
      const int tg = t0 + tloc;
      if (tg < 600) {
        const u16* kp = qkv + bbase + (size_t)tg * 3072 + 1024 + h * 64 + dhalf;
        const u16* vp = kp + 1024;
#pragma unroll
        for (int c = 0; c < 4; ++c)
          *(uintx4*)&K_ld[tloc * 72 + dhalf + c * 8] = *(const uintx4*)(kp + c * 8);
#pragma unroll
        for (int c = 0; c < 4; ++c) {
          shortx8 vv = *(const shortx8*)(vp + c * 8);
#pragma unroll
          for (int e = 0; e < 8; ++e)
            Vt[(dhalf + c * 8 + e) * 136 + tloc] = (u16)vv[e];
        }
      } else {
        const uintx4 z4 = (uintx4){0, 0, 0, 0};
#pragma unroll
        for (int c = 0; c < 4; ++c)
          *(uintx4*)&K_ld[tloc * 72 + dhalf + c * 8] = z4;
#pragma unroll
        for (int c = 0; c < 4; ++c)
#pragma unroll
          for (int e = 0; e < 8; ++e)
            Vt[(dhalf + c * 8 + e) * 136 + tloc] = 0;
      }
    }
    __syncthreads();

#pragma unroll
    for (int sub = 0; sub < 2; ++sub) {
      floatx4 S[8];
      __builtin_amdgcn_s_setprio(1);
#pragma unroll
      for (int jb = 0; jb < 8; ++jb) {
        S[jb] = (floatx4){0.f, 0.f, 0.f, 0.f};
#pragma unroll
        for (int ks = 0; ks < 2; ++ks) {
          shortx8 bk = *(const shortx8*)&K_ld[(jb * 16 + lq) * 72 + ks * 32 + g * 8];
          S[jb] = __builtin_amdgcn_mfma_f32_16x16x32_bf16(aq[sub][ks], bk, S[jb], 0, 0, 0);
        }
      }
      __builtin_amdgcn_s_setprio(0);
      if (ch == 4) {  // only last chunk has t >= 600
#pragma unroll
        for (int jb = 0; jb < 8; ++jb) {
          const bool ok = (t0 + jb * 16 + lq) < 600;
#pragma unroll
          for (int r = 0; r < 4; ++r) S[jb][r] = ok ? S[jb][r] * 0.125f : -1e30f;
        }
      } else {
#pragma unroll
        for (int jb = 0; jb < 8; ++jb)
#pragma unroll
          for (int r = 0; r < 4; ++r) S[jb][r] *= 0.125f;
      }

      // row max + T13 defer-max (THR=8): skip rescale when max growth small
      float vmax[4];
      bool need = false;
#pragma unroll
      for (int r = 0; r < 4; ++r) {
        float v = S[0][r];
#pragma unroll
        for (int jb = 1; jb < 8; ++jb) v = fmaxf(v, S[jb][r]);
        v = fmaxf(v, __shfl_xor(v, 1));
        v = fmaxf(v, __shfl_xor(v, 2));
        v = fmaxf(v, __shfl_xor(v, 4));
        v = fmaxf(v, __shfl_xor(v, 8));
        vmax[r] = v;
        need |= (v > m[sub][r] + 8.0f);
      }
      if (__any(need ? 1 : 0)) {
#pragma unroll
        for (int r = 0; r < 4; ++r) {
          const float mn = fmaxf(m[sub][r], vmax[r]);
          const float sc = __expf(m[sub][r] - mn);
          m[sub][r] = mn;
          l[sub][r] *= sc;
#pragma unroll
          for (int db = 0; db < 4; ++db) Oa[sub][db][r] *= sc;
        }
      }

      float sums[4] = {0.f, 0.f, 0.f, 0.f};
#pragma unroll
      for (int jb = 0; jb < 8; ++jb)
#pragma unroll
        for (int r = 0; r < 4; ++r) {
          const float p = __expf(S[jb][r] - m[sub][r]);
          sums[r] += p;
          P_ld[w][(g * 4 + r) * 136 + jb * 16 + lq] = f2bf(p);
        }
#pragma unroll
      for (int r = 0; r < 4; ++r) {
        float v = sums[r];
        v += __shfl_xor(v, 1);
        v += __shfl_xor(v, 2);
        v += __shfl_xor(v, 4);
        v += __shfl_xor(v, 8);
        l[sub][r] += v;
      }

      __builtin_amdgcn_s_setprio(1);
#pragma unroll
      for (int ks = 0; ks < 4; ++ks) {
        shortx8 ap = *(const shortx8*)&P_ld[w][lq * 136 + ks * 32 + g * 8];
#pragma unroll
        for (int db = 0; db < 4; ++db) {
          shortx8 bv = *(const shortx8*)&Vt[(db * 16 + lq) * 136 + ks * 32 + g * 8];
          Oa[sub][db] = __builtin_amdgcn_mfma_f32_16x16x32_bf16(ap, bv, Oa[sub][db], 0, 0, 0);
        }
      }
      __builtin_amdgcn_s_setprio(0);
    }
  }

  // epilogue: contiguous ctx[b][s][h*64 + d], d = db*16 + lq
#pragma unroll
  for (int sub = 0; sub < 2; ++sub) {
#pragma unroll
    for (int r = 0; r < 4; ++r) {
      const int sg = q0 + sub * 16 + g * 4 + r;
      if (sg < 600) {
        const float inv = 1.f / l[sub][r];
        u16* orow = aout + ((size_t)(b * 600 + sg)) * 1024 + h * 64;
#pragma unroll
        for (int db = 0; db < 4; ++db)
          orow[db * 16 + lq] = f2bf(Oa[sub][db][r] * inv);
      }
    }
  }
}

// ---------------------------------------------------------------------------
// LayerNorm over 1024 (strided rows): one block per row, biased var, eps 1e-5.
// ---------------------------------------------------------------------------
__launch_bounds__(256)
__global__ void ln_kernel(const u16* __restrict__ y, int ldy,
                          const float* __restrict__ g, const float* __restrict__ be,
                          u16* __restrict__ o, int ldo) {
  const int row = blockIdx.x, tid = threadIdx.x;
  const int lane = tid & 63, wv = tid >> 6;
  const u16* yr = y + (size_t)row * ldy;
  const int c = tid * 4;
  const uintx2 yv = *(const uintx2*)&yr[c];
  float v0 = bf2f((u16)(yv[0] & 0xffffu)), v1 = bf2f((u16)(yv[0] >> 16));
  float v2 = bf2f((u16)(yv[1] & 0xffffu)), v3 = bf2f((u16)(yv[1] >> 16));
  float s = v0 + v1 + v2 + v3;
  float q = v0 * v0 + v1 * v1 + v2 * v2 + v3 * v3;
#pragma unroll
  for (int m = 32; m; m >>= 1) {
    s += __shfl_xor(s, m);
    q += __shfl_xor(q, m);
  }
  __shared__ float red[2][4];
  if (lane == 0) {
    red[0][wv] = s;
    red[1][wv] = q;
  }
  __syncthreads();
  s = red[0][0] + red[0][1] + red[0][2] + red[0][3];
  q = red[1][0] + red[1][1] + red[1][2] + red[1][3];
  const float mu = s * (1.f / 1024.f);
  const float var = q * (1.f / 1024.f) - mu * mu;
  const float rstd = rsqrtf(var + 1e-5f);
  const float4 gv = *(const float4*)&g[c];
  const float4 bev = *(const float4*)&be[c];
  const float o0 = (v0 - mu) * rstd * gv.x + bev.x;
  const float o1 = (v1 - mu) * rstd * gv.y + bev.y;
  const float o2 = (v2 - mu) * rstd * gv.z + bev.z;
  const float o3 = (v3 - mu) * rstd * gv.w + bev.w;
  uintx2 ov;
  ov[0] = (u32)f2bf(o0) | ((u32)f2bf(o1) << 16);
  ov[1] = (u32)f2bf(o2) | ((u32)f2bf(o3) << 16);
  *(uintx2*)&o[(size_t)row * ldo + c] = ov;
}

// ---------------------------------------------------------------------------
// out: out[m][f] = h[m][:] . outW[:][f] + outb[f], f<9. One wave per row. fp32 out.
// ---------------------------------------------------------------------------
__launch_bounds__(256)
__global__ void out_kernel(const u16* __restrict__ h, const float* __restrict__ W,
                           const float* __restrict__ bias, float* __restrict__ out) {
  const int m = blockIdx.x * 4 + (threadIdx.x >> 6);
  const int lane = threadIdx.x & 63;
  float acc[9];
#pragma unroll
  for (int f = 0; f < 9; ++f) acc[f] = 0.f;
  const u16* hr = h + (size_t)m * 1024;
#pragma unroll 4
  for (int j = 0; j < 16; ++j) {
    const int k = lane + j * 64;
    const float hv = bf2f(hr[k]);
    const float* wr = W + (size_t)k * 9;
#pragma unroll
    for (int f = 0; f < 9; ++f) acc[f] += hv * wr[f];
  }
#pragma unroll
  for (int f = 0; f < 9; ++f)
#pragma unroll
    for (int mm = 32; mm; mm >>= 1) acc[f] += __shfl_xor(acc[f], mm);
  if (lane < 9) out[(size_t)m * 9 + lane] = acc[lane] + bias[lane];
}

// ---------------------------------------------------------------------------
extern "C" void kernel_launch(void* const* d_in, const int* in_sizes, int n_in,
                              void* d_out, int out_size, void* d_ws, size_t ws_size,
                              hipStream_t stream) {
  (void)in_sizes; (void)n_in; (void)out_size; (void)ws_size;
  const float* x     = (const float*)d_in[0];
  const float* encW  = (const float*)d_in[1];
  const float* encB  = (const float*)d_in[2];
  const float* Wq    = (const float*)d_in[3];
  const float* bq    = (const float*)d_in[4];
  const float* Wk    = (const float*)d_in[5];
  const float* bk    = (const float*)d_in[6];
  const float* Wv    = (const float*)d_in[7];
  const float* bv    = (const float*)d_in[8];
  const float* Wo    = (const float*)d_in[9];
  const float* bo    = (const float*)d_in[10];
  const float* W1    = (const float*)d_in[11];
  const float* b1    = (const float*)d_in[12];
  const float* W2    = (const float*)d_in[13];
  const float* b2    = (const float*)d_in[14];
  const float* ln1w  = (const float*)d_in[15];
  const float* ln1b  = (const float*)d_in[16];
  const float* ln2w  = (const float*)d_in[17];
  const float* ln2b  = (const float*)d_in[18];
  const float* outW  = (const float*)d_in[19];
  const float* outB  = (const float*)d_in[20];
  float* out = (float*)d_out;

  char* ws = (char*)d_ws;
  size_t off = 0;
  auto alloc = [&](size_t bytes) -> void* {
    void* p = ws + off;
    off += (bytes + 255) & ~(size_t)255;
    return p;
  };
  u16* h    = (u16*)alloc(19660800ull * 2);   // [19200][1024]
  u16* qkv  = (u16*)alloc(58982400ull * 2);   // [19200][3072]
  u16* abuf = (u16*)alloc(19660800ull * 2);   // ctx [19200][1024] (h*64+d layout)
  u16* Bqkv = (u16*)alloc(6291456ull * 2);    // [2][3072][1024]
  u16* Bwo  = (u16*)alloc(2097152ull * 2);    // [2][1024][1024] permuted-transposed
  u16* Bw1  = (u16*)alloc(2097152ull * 2);
  u16* Bw2  = (u16*)alloc(2097152ull * 2);
  float* bqkv = (float*)alloc(6144ull * 4);   // [2][3072] fp32
  // column-slot aliases inside qkv (stride 3072), reusing dead q/k/v slots:
  u16* ybuf = qkv;          // q-slot: Wo-gemm output (q dead after attention)
  u16* x1   = qkv + 1024;   // k-slot: ln1 output
  u16* mid  = qkv + 2048;   // v-slot: fc2/ELU output
  u16* y2   = abuf;         // dense: fc1 output (+x1 residual); abuf dead by then

  pack_qkv_t<<<dim3(16, 32), 256, 0, stream>>>(Wq, Bqkv);
  pack_qkv_t<<<dim3(16, 32), 256, 0, stream>>>(Wk, Bqkv + 1048576);
  pack_qkv_t<<<dim3(16, 32), 256, 0, stream>>>(Wv, Bqkv + 2097152);
  pack_wo_t<<<dim3(256, 2), 256, 0, stream>>>(Wo, Bwo);
  pack_sq_t<<<dim3(256, 2), 256, 0, stream>>>(W1, Bw1);
  pack_sq_t<<<dim3(256, 2), 256, 0, stream>>>(W2, Bw2);
  pack_bias<<<24, 256, 0, stream>>>(bq, bk, bv, bqkv);
  enc_kernel<<<76800, 256, 0, stream>>>(x, encW, encB, h);

  for (int l = 0; l < 2; ++l) {
    gemm_bt_wide<0><<<dim3(12, 150), 512, 0, stream>>>(
        h, 1024, Bqkv + (size_t)l * 3145728, bqkv + l * 3072, nullptr, 0, qkv, 3072);
    attn_mfma<<<dim3(5, 512), 256, 0, stream>>>(qkv, abuf);
    gemm_bt_wide<1><<<dim3(4, 150), 512, 0, stream>>>(
        abuf, 1024, Bwo + (size_t)l * 1048576, bo + l * 1024, h, 1024, ybuf, 3072);
    ln_kernel<<<19200, 256, 0, stream>>>(ybuf, 3072, ln1w + l * 1024, ln1b + l * 1024, x1, 3072);
    gemm_bt_wide<2><<<dim3(4, 150), 512, 0, stream>>>(
        x1, 3072, Bw2 + (size_t)l * 1048576, b2 + l * 1024, nullptr, 0, mid, 3072);
    gemm_bt_wide<1><<<dim3(4, 150), 512, 0, stream>>>(
        mid, 3072, Bw1 + (size_t)l * 1048576, b1 + l * 1024, x1, 3072, y2, 1024);
    ln_kernel<<<19200, 256, 0, stream>>>(y2, 1024, ln2w + l * 1024, ln2b + l * 1024, h, 1024);
  }
  out_kernel<<<4800, 256, 0, stream>>>(h, outW, outB, out);
}